// Round 1
// baseline (282.232 us; speedup 1.0000x reference)
//
#include <hip/hip_runtime.h>
#include <hip/hip_bf16.h>

#define NBATCH 2
#define SEQ 2048
#define DMODEL 1024
#define NHEAD 16
#define HDIM 64
#define ROWS (NBATCH*SEQ)

typedef __attribute__((ext_vector_type(8))) short bf16x8;
typedef __attribute__((ext_vector_type(4))) float f32x4;

#define MFMA16 __builtin_amdgcn_mfma_f32_16x16x32_bf16

static __device__ __forceinline__ unsigned short f2bf(float f) {
    unsigned int u = __float_as_uint(f);
    u += 0x7fffu + ((u >> 16) & 1u);
    return (unsigned short)(u >> 16);
}

// ---------------- fp32 -> bf16 convert (row-major preserved) ----------------
__global__ __launch_bounds__(256) void cvt_kernel(const float* __restrict__ src,
                                                  unsigned short* __restrict__ dst, int n8) {
    int i = blockIdx.x * 256 + threadIdx.x;
    if (i >= n8) return;
    const float4* s4 = (const float4*)src;
    float4 a = s4[2 * i], b = s4[2 * i + 1];
    union { bf16x8 v; unsigned short u[8]; } o;
    o.u[0] = f2bf(a.x); o.u[1] = f2bf(a.y); o.u[2] = f2bf(a.z); o.u[3] = f2bf(a.w);
    o.u[4] = f2bf(b.x); o.u[5] = f2bf(b.y); o.u[6] = f2bf(b.z); o.u[7] = f2bf(b.w);
    *(bf16x8*)(dst + (size_t)i * 8) = o.v;
}

// ---------------- weight transpose + convert: WT[n][k] = bf16(W[k][n]) ----------------
__global__ __launch_bounds__(256) void wtrans_kernel(const float* __restrict__ W0, const float* __restrict__ W1,
                                                     const float* __restrict__ W2,
                                                     unsigned short* __restrict__ T0, unsigned short* __restrict__ T1,
                                                     unsigned short* __restrict__ T2) {
    const float* W = blockIdx.z == 0 ? W0 : (blockIdx.z == 1 ? W1 : W2);
    unsigned short* T = blockIdx.z == 0 ? T0 : (blockIdx.z == 1 ? T1 : T2);
    __shared__ float tile[64][65];
    int rb = blockIdx.y * 64, cb = blockIdx.x * 64;
    int tid = threadIdx.x;
    #pragma unroll
    for (int rep = 0; rep < 16; ++rep) {
        int idx = rep * 256 + tid; int r = idx >> 6, c = idx & 63;
        tile[r][c] = W[(size_t)(rb + r) * DMODEL + cb + c];
    }
    __syncthreads();
    #pragma unroll
    for (int rep = 0; rep < 16; ++rep) {
        int idx = rep * 256 + tid; int r = idx >> 6, c = idx & 63;
        T[(size_t)(cb + r) * DMODEL + rb + c] = f2bf(tile[c][r]);
    }
}

// ---------------- projection GEMM ----------------
// mode 0/1 (Q,K): C = X @ W, scatter to [B][H][S][D] bf16
// mode 2   (V)  : swapped operands (C^T), scatter to [B][H][D][S] bf16
__global__ __launch_bounds__(256) void proj_kernel(
        const unsigned short* __restrict__ Xq, const unsigned short* __restrict__ Xk,
        const unsigned short* __restrict__ Xv,
        const unsigned short* __restrict__ WTq, const unsigned short* __restrict__ WTk,
        const unsigned short* __restrict__ WTv,
        unsigned short* __restrict__ qp, unsigned short* __restrict__ kp,
        unsigned short* __restrict__ vtp) {
    const int mode = blockIdx.z;
    const unsigned short* X  = mode == 0 ? Xq  : (mode == 1 ? Xk  : Xv);
    const unsigned short* WT = mode == 0 ? WTq : (mode == 1 ? WTk : WTv);

    __shared__ short As[128 * 64];  // X rows   [128][64] bf16, swizzled
    __shared__ short Bs[128 * 64];  // WT rows  [128][64] bf16, swizzled

    const int tid = threadIdx.x, lane = tid & 63, w = tid >> 6;
    const int wr = w >> 1, wc = w & 1;
    const int rowBase = blockIdx.y * 128;   // X-row (b*S+s) dimension
    const int colBase = blockIdx.x * 128;   // W-col (h*D+d) dimension

    const int Xwave = (mode < 2) ? wr : wc;
    const int Wwave = (mode < 2) ? wc : wr;

    f32x4 acc[4][4];
    #pragma unroll
    for (int i = 0; i < 4; ++i)
        #pragma unroll
        for (int j = 0; j < 4; ++j) acc[i][j] = (f32x4){0.f, 0.f, 0.f, 0.f};

    for (int kt = 0; kt < DMODEL / 64; ++kt) {
        #pragma unroll
        for (int rr = 0; rr < 4; ++rr) {
            int idx = rr * 256 + tid; int r = idx >> 3; int c8 = idx & 7;
            int4 va = *(const int4*)(X + (size_t)(rowBase + r) * DMODEL + kt * 64 + c8 * 8);
            *(int4*)((char*)As + r * 128 + ((c8 * 16) ^ ((r & 7) << 4))) = va;
            int4 vb = *(const int4*)(WT + (size_t)(colBase + r) * DMODEL + kt * 64 + c8 * 8);
            *(int4*)((char*)Bs + r * 128 + ((c8 * 16) ^ ((r & 7) << 4))) = vb;
        }
        __syncthreads();
        #pragma unroll
        for (int ks = 0; ks < 2; ++ks) {
            const int kbyte = ks * 64 + ((lane >> 4) * 16);
            bf16x8 xf[4], wf[4];
            #pragma unroll
            for (int i = 0; i < 4; ++i) {
                int xr = Xwave * 64 + i * 16 + (lane & 15);
                xf[i] = *(const bf16x8*)((const char*)As + xr * 128 + (kbyte ^ ((xr & 7) << 4)));
                int wrow = Wwave * 64 + i * 16 + (lane & 15);
                wf[i] = *(const bf16x8*)((const char*)Bs + wrow * 128 + (kbyte ^ ((wrow & 7) << 4)));
            }
            if (mode < 2) {
                #pragma unroll
                for (int i = 0; i < 4; ++i)
                    #pragma unroll
                    for (int j = 0; j < 4; ++j)
                        acc[i][j] = MFMA16(xf[i], wf[j], acc[i][j], 0, 0, 0);
            } else {
                #pragma unroll
                for (int i = 0; i < 4; ++i)
                    #pragma unroll
                    for (int j = 0; j < 4; ++j)
                        acc[i][j] = MFMA16(wf[i], xf[j], acc[i][j], 0, 0, 0);
            }
        }
        __syncthreads();
    }

    if (mode < 2) {
        unsigned short* outp = (mode == 0) ? qp : kp;
        #pragma unroll
        for (int i = 0; i < 4; ++i)
            #pragma unroll
            for (int j = 0; j < 4; ++j)
                #pragma unroll
                for (int r = 0; r < 4; ++r) {
                    int grow = rowBase + wr * 64 + i * 16 + (lane >> 4) * 4 + r;  // b*S+s
                    int gcol = colBase + wc * 64 + j * 16 + (lane & 15);          // h*D+d
                    int b = grow >> 11, s = grow & 2047, h = gcol >> 6, d = gcol & 63;
                    outp[((size_t)(b * NHEAD + h) * SEQ + s) * HDIM + d] = f2bf(acc[i][j][r]);
                }
    } else {
        #pragma unroll
        for (int i = 0; i < 4; ++i)
            #pragma unroll
            for (int j = 0; j < 4; ++j)
                #pragma unroll
                for (int r = 0; r < 4; ++r) {
                    int gcol = colBase + wr * 64 + i * 16 + (lane >> 4) * 4 + r;  // h*D+d
                    int grow = rowBase + wc * 64 + j * 16 + (lane & 15);          // b*S+s
                    int b = grow >> 11, s = grow & 2047, h = gcol >> 6, d = gcol & 63;
                    vtp[((size_t)(b * NHEAD + h) * HDIM + d) * SEQ + s] = f2bf(acc[i][j][r]);
                }
    }
}

// ---------------- flash attention ----------------
// grid (S/64, H, B); 4 waves; wave w handles q-rows [qt*64 + w*16, +16)
__global__ __launch_bounds__(256) void attn_kernel(
        const unsigned short* __restrict__ qp, const unsigned short* __restrict__ kp,
        const unsigned short* __restrict__ vtp, const int* __restrict__ vlenp,
        float* __restrict__ out) {
    const int tid = threadIdx.x, lane = tid & 63, w = tid >> 6;
    const int qt = blockIdx.x, h = blockIdx.y, b = blockIdx.z;
    const int vlen = vlenp[b];

    __shared__ short Ks[64 * 64];        // [key][d] swizzled
    __shared__ short Vs[64 * 64];        // [d][key] swizzled (V^T layout)
    __shared__ short Ps[4][16 * 64];     // per-wave P [q][key] swizzled

    const size_t headQ = (size_t)(b * NHEAD + h) * SEQ * HDIM;
    const size_t headV = (size_t)(b * NHEAD + h) * HDIM * SEQ;

    const int qrow = qt * 64 + w * 16 + (lane & 15);
    bf16x8 qf[2];
    #pragma unroll
    for (int ks = 0; ks < 2; ++ks)
        qf[ks] = *(const bf16x8*)(qp + headQ + (size_t)qrow * HDIM + ks * 32 + (lane >> 4) * 8);

    f32x4 acc_o[4];
    #pragma unroll
    for (int dt = 0; dt < 4; ++dt) acc_o[dt] = (f32x4){0.f, 0.f, 0.f, 0.f};
    float m_run[4] = {-1e30f, -1e30f, -1e30f, -1e30f};
    float l_run[4] = {0.f, 0.f, 0.f, 0.f};

    short* Pw = &Ps[w][0];

    for (int kv = 0; kv < SEQ / 64; ++kv) {
        const int kvBase = kv * 64;
        #pragma unroll
        for (int rr = 0; rr < 2; ++rr) {
            int idx = rr * 256 + tid; int r = idx >> 3, c8 = idx & 7;
            int4 va = *(const int4*)(kp + headQ + (size_t)(kvBase + r) * HDIM + c8 * 8);
            *(int4*)((char*)Ks + r * 128 + ((c8 * 16) ^ ((r & 7) << 4))) = va;
            int4 vb = *(const int4*)(vtp + headV + (size_t)r * SEQ + kvBase + c8 * 8);
            *(int4*)((char*)Vs + r * 128 + ((c8 * 16) ^ ((r & 7) << 4))) = vb;
        }
        __syncthreads();

        // QK^T: sa[nt] rows=q (lane>>4)*4+reg, cols=key nt*16+(lane&15)
        f32x4 sa[4];
        #pragma unroll
        for (int nt = 0; nt < 4; ++nt) sa[nt] = (f32x4){0.f, 0.f, 0.f, 0.f};
        #pragma unroll
        for (int ks = 0; ks < 2; ++ks) {
            const int kbyte = ks * 64 + (lane >> 4) * 16;
            #pragma unroll
            for (int nt = 0; nt < 4; ++nt) {
                int kr = nt * 16 + (lane & 15);
                bf16x8 kf = *(const bf16x8*)((const char*)Ks + kr * 128 + (kbyte ^ ((kr & 7) << 4)));
                sa[nt] = MFMA16(qf[ks], kf, sa[nt], 0, 0, 0);
            }
        }

        // online softmax per q-row (reg r)
        float p[4][4];
        #pragma unroll
        for (int r = 0; r < 4; ++r) {
            float rmax = -1e30f;
            #pragma unroll
            for (int nt = 0; nt < 4; ++nt) {
                float sv = sa[nt][r] * 0.125f;
                if (kvBase + nt * 16 + (lane & 15) >= vlen) sv = -1e9f;
                p[nt][r] = sv;
                rmax = fmaxf(rmax, sv);
            }
            #pragma unroll
            for (int m = 1; m < 16; m <<= 1) rmax = fmaxf(rmax, __shfl_xor(rmax, m));
            float mnew = fmaxf(m_run[r], rmax);
            float al = __expf(m_run[r] - mnew);
            float rs = 0.f;
            #pragma unroll
            for (int nt = 0; nt < 4; ++nt) {
                p[nt][r] = __expf(p[nt][r] - mnew);
                rs += p[nt][r];
            }
            #pragma unroll
            for (int m = 1; m < 16; m <<= 1) rs += __shfl_xor(rs, m);
            l_run[r] = l_run[r] * al + rs;
            m_run[r] = mnew;
            #pragma unroll
            for (int dt = 0; dt < 4; ++dt) acc_o[dt][r] *= al;
        }

        // P -> LDS (bf16, per-wave region; same-wave so no barrier needed)
        #pragma unroll
        for (int r = 0; r < 4; ++r)
            #pragma unroll
            for (int nt = 0; nt < 4; ++nt) {
                int pr = (lane >> 4) * 4 + r;
                int pc = nt * 16 + (lane & 15);
                *(unsigned short*)((char*)Pw + pr * 128 + ((pc * 2) ^ ((pr & 7) << 4))) = f2bf(p[nt][r]);
            }

        // PV: acc_o[dt] += P[16x64] @ V[64x(dt*16..)]
        #pragma unroll
        for (int ks = 0; ks < 2; ++ks) {
            const int kbyte = ks * 64 + (lane >> 4) * 16;
            int prr = lane & 15;
            bf16x8 pf = *(const bf16x8*)((const char*)Pw + prr * 128 + (kbyte ^ ((prr & 7) << 4)));
            #pragma unroll
            for (int dt = 0; dt < 4; ++dt) {
                int vr = dt * 16 + (lane & 15);
                bf16x8 vf = *(const bf16x8*)((const char*)Vs + vr * 128 + (kbyte ^ ((vr & 7) << 4)));
                acc_o[dt] = MFMA16(pf, vf, acc_o[dt], 0, 0, 0);
            }
        }
        __syncthreads();
    }

    #pragma unroll
    for (int r = 0; r < 4; ++r) {
        float inv = 1.0f / l_run[r];
        int s = qt * 64 + w * 16 + (lane >> 4) * 4 + r;
        #pragma unroll
        for (int dt = 0; dt < 4; ++dt) {
            int col = h * HDIM + dt * 16 + (lane & 15);
            out[(size_t)(b * SEQ + s) * DMODEL + col] = acc_o[dt][r] * inv;
        }
    }
}

extern "C" void kernel_launch(void* const* d_in, const int* in_sizes, int n_in,
                              void* d_out, int out_size, void* d_ws, size_t ws_size,
                              hipStream_t stream) {
    const float* Q  = (const float*)d_in[0];
    const float* K  = (const float*)d_in[1];
    const float* V  = (const float*)d_in[2];
    const int* V_len = (const int*)d_in[3];
    const float* WQ = (const float*)d_in[4];
    const float* WK = (const float*)d_in[5];
    const float* WV = (const float*)d_in[6];
    float* out = (float*)d_out;

    char* ws = (char*)d_ws;
    const size_t MB = 1024 * 1024;
    unsigned short* Xq  = (unsigned short*)(ws + 0 * MB);   // 8 MiB each
    unsigned short* Xk  = (unsigned short*)(ws + 8 * MB);
    unsigned short* Xv  = (unsigned short*)(ws + 16 * MB);
    unsigned short* WTq = (unsigned short*)(ws + 24 * MB);  // 2 MiB each
    unsigned short* WTk = (unsigned short*)(ws + 26 * MB);
    unsigned short* WTv = (unsigned short*)(ws + 28 * MB);
    unsigned short* qpj = (unsigned short*)(ws + 30 * MB);  // [B][H][S][D] 8 MiB
    unsigned short* kpj = (unsigned short*)(ws + 38 * MB);  // [B][H][S][D] 8 MiB
    unsigned short* vtp = (unsigned short*)(ws + 46 * MB);  // [B][H][D][S] 8 MiB

    const int n8 = ROWS * DMODEL / 8;  // 524288
    cvt_kernel<<<dim3((n8 + 255) / 256), 256, 0, stream>>>(Q, Xq, n8);
    cvt_kernel<<<dim3((n8 + 255) / 256), 256, 0, stream>>>(K, Xk, n8);
    cvt_kernel<<<dim3((n8 + 255) / 256), 256, 0, stream>>>(V, Xv, n8);
    wtrans_kernel<<<dim3(16, 16, 3), 256, 0, stream>>>(WQ, WK, WV, WTq, WTk, WTv);
    proj_kernel<<<dim3(DMODEL / 128, ROWS / 128, 3), 256, 0, stream>>>(
        Xq, Xk, Xv, WTq, WTk, WTv, qpj, kpj, vtp);
    attn_kernel<<<dim3(SEQ / 64, NHEAD, NBATCH), 256, 0, stream>>>(qpj, kpj, vtp, V_len, out);
}

// Round 2
// 136.126 us; speedup vs baseline: 2.0733x; 2.0733x over previous
//
#include <hip/hip_runtime.h>
#include <hip/hip_bf16.h>

#define NBATCH 2
#define SEQ 2048
#define DMODEL 1024
#define NHEAD 16
#define HDIM 64
#define ROWS (NBATCH*SEQ)

typedef __attribute__((ext_vector_type(8))) short bf16x8;
typedef __attribute__((ext_vector_type(4))) float f32x4;

#define MFMA16 __builtin_amdgcn_mfma_f32_16x16x32_bf16

static __device__ __forceinline__ unsigned short f2bf(float f) {
    unsigned int u = __float_as_uint(f);
    u += 0x7fffu + ((u >> 16) & 1u);
    return (unsigned short)(u >> 16);
}

// async global->LDS, 16B per lane; LDS dest = wave-uniform base + lane*16
static __device__ __forceinline__ void gld16(const unsigned short* g, unsigned short* l) {
    __builtin_amdgcn_global_load_lds(
        (const __attribute__((address_space(1))) unsigned int*)g,
        (__attribute__((address_space(3))) unsigned int*)l,
        16, 0, 0);
}

// ---------------- fp32 -> bf16 convert, all three inputs in one launch ----------------
__global__ __launch_bounds__(256) void cvt_kernel(const float* __restrict__ Q, const float* __restrict__ K,
                                                  const float* __restrict__ V,
                                                  unsigned short* __restrict__ dq, unsigned short* __restrict__ dk,
                                                  unsigned short* __restrict__ dv, int n8) {
    int i = blockIdx.x * 256 + threadIdx.x;
    if (i >= n8) return;
    const float* src = blockIdx.z == 0 ? Q : (blockIdx.z == 1 ? K : V);
    unsigned short* dst = blockIdx.z == 0 ? dq : (blockIdx.z == 1 ? dk : dv);
    const float4* s4 = (const float4*)src;
    float4 a = s4[2 * i], b = s4[2 * i + 1];
    union { bf16x8 v; unsigned short u[8]; } o;
    o.u[0] = f2bf(a.x); o.u[1] = f2bf(a.y); o.u[2] = f2bf(a.z); o.u[3] = f2bf(a.w);
    o.u[4] = f2bf(b.x); o.u[5] = f2bf(b.y); o.u[6] = f2bf(b.z); o.u[7] = f2bf(b.w);
    *(bf16x8*)(dst + (size_t)i * 8) = o.v;
}

// ---------------- weight transpose + convert: WT[n][k] = bf16(W[k][n]) ----------------
__global__ __launch_bounds__(256) void wtrans_kernel(const float* __restrict__ W0, const float* __restrict__ W1,
                                                     const float* __restrict__ W2,
                                                     unsigned short* __restrict__ T0, unsigned short* __restrict__ T1,
                                                     unsigned short* __restrict__ T2) {
    const float* W = blockIdx.z == 0 ? W0 : (blockIdx.z == 1 ? W1 : W2);
    unsigned short* T = blockIdx.z == 0 ? T0 : (blockIdx.z == 1 ? T1 : T2);
    __shared__ float tile[64][65];
    int rb = blockIdx.y * 64, cb = blockIdx.x * 64;
    int tid = threadIdx.x;
    #pragma unroll
    for (int rep = 0; rep < 16; ++rep) {
        int idx = rep * 256 + tid; int r = idx >> 6, c = idx & 63;
        tile[r][c] = W[(size_t)(rb + r) * DMODEL + cb + c];
    }
    __syncthreads();
    #pragma unroll
    for (int rep = 0; rep < 16; ++rep) {
        int idx = rep * 256 + tid; int r = idx >> 6, c = idx & 63;
        T[(size_t)(cb + r) * DMODEL + rb + c] = f2bf(tile[c][r]);
    }
}

// ---------------- projection GEMM (m97 structure: global_load_lds, 2 barriers/k-tile) ----------------
// mode 0/1 (Q,K): C = X @ W, scatter to [B][H][S][D] bf16
// mode 2   (V)  : swapped operands (C^T), scatter to [B][H][D][S] bf16
__global__ __launch_bounds__(256) void proj_kernel(
        const unsigned short* __restrict__ Xq, const unsigned short* __restrict__ Xk,
        const unsigned short* __restrict__ Xv,
        const unsigned short* __restrict__ WTq, const unsigned short* __restrict__ WTk,
        const unsigned short* __restrict__ WTv,
        unsigned short* __restrict__ qp, unsigned short* __restrict__ kp,
        unsigned short* __restrict__ vtp) {
    const int mode = blockIdx.z;
    const unsigned short* X  = mode == 0 ? Xq  : (mode == 1 ? Xk  : Xv);
    const unsigned short* WT = mode == 0 ? WTq : (mode == 1 ? WTk : WTv);

    __shared__ unsigned short As[128 * 64];  // [128 rows][64 shorts], swizzle via pre-swizzled source
    __shared__ unsigned short Bs[128 * 64];

    const int tid = threadIdx.x, lane = tid & 63, w = tid >> 6;
    const int wr = w >> 1, wc = w & 1;
    const int rowBase = blockIdx.y * 128;   // X-row (b*S+s)
    const int colBase = blockIdx.x * 128;   // W-col (h*D+d)

    const int Xwave = (mode < 2) ? wr : wc;
    const int Wwave = (mode < 2) ? wc : wr;

    // staging geometry: chunk c (0..15) = 8 rows; wave w stages chunks w*4..w*4+3
    const int rloc = lane >> 3;                        // row within chunk 0..7
    const int ssw  = ((lane & 7) * 8) ^ (rloc * 8);    // swizzled short-offset within 64-short k-slice

    f32x4 acc[4][4];
    #pragma unroll
    for (int i = 0; i < 4; ++i)
        #pragma unroll
        for (int j = 0; j < 4; ++j) acc[i][j] = (f32x4){0.f, 0.f, 0.f, 0.f};

    for (int kt = 0; kt < DMODEL / 64; ++kt) {
        #pragma unroll
        for (int j = 0; j < 4; ++j) {
            int c = w * 4 + j;
            int r = c * 8 + rloc;
            gld16(X  + (size_t)(rowBase + r) * DMODEL + kt * 64 + ssw, &As[c * 512]);
            gld16(WT + (size_t)(colBase + r) * DMODEL + kt * 64 + ssw, &Bs[c * 512]);
        }
        __syncthreads();   // drains vmcnt before barrier
        #pragma unroll
        for (int ks = 0; ks < 2; ++ks) {
            const int kbyte = ks * 64 + ((lane >> 4) * 16);
            bf16x8 xf[4], wf[4];
            #pragma unroll
            for (int i = 0; i < 4; ++i) {
                int xr = Xwave * 64 + i * 16 + (lane & 15);
                xf[i] = *(const bf16x8*)((const char*)As + xr * 128 + (kbyte ^ ((xr & 7) << 4)));
                int wrow = Wwave * 64 + i * 16 + (lane & 15);
                wf[i] = *(const bf16x8*)((const char*)Bs + wrow * 128 + (kbyte ^ ((wrow & 7) << 4)));
            }
            if (mode < 2) {
                #pragma unroll
                for (int i = 0; i < 4; ++i)
                    #pragma unroll
                    for (int j = 0; j < 4; ++j)
                        acc[i][j] = MFMA16(xf[i], wf[j], acc[i][j], 0, 0, 0);
            } else {
                #pragma unroll
                for (int i = 0; i < 4; ++i)
                    #pragma unroll
                    for (int j = 0; j < 4; ++j)
                        acc[i][j] = MFMA16(wf[i], xf[j], acc[i][j], 0, 0, 0);
            }
        }
        __syncthreads();
    }

    if (mode < 2) {
        unsigned short* outp = (mode == 0) ? qp : kp;
        #pragma unroll
        for (int i = 0; i < 4; ++i)
            #pragma unroll
            for (int j = 0; j < 4; ++j)
                #pragma unroll
                for (int r = 0; r < 4; ++r) {
                    int grow = rowBase + wr * 64 + i * 16 + (lane >> 4) * 4 + r;  // b*S+s
                    int gcol = colBase + wc * 64 + j * 16 + (lane & 15);          // h*D+d
                    int b = grow >> 11, s = grow & 2047, h = gcol >> 6, d = gcol & 63;
                    outp[((size_t)(b * NHEAD + h) * SEQ + s) * HDIM + d] = f2bf(acc[i][j][r]);
                }
    } else {
        #pragma unroll
        for (int i = 0; i < 4; ++i)
            #pragma unroll
            for (int j = 0; j < 4; ++j)
                #pragma unroll
                for (int r = 0; r < 4; ++r) {
                    int gcol = colBase + wr * 64 + i * 16 + (lane >> 4) * 4 + r;  // h*D+d
                    int grow = rowBase + wc * 64 + j * 16 + (lane & 15);          // b*S+s
                    int b = grow >> 11, s = grow & 2047, h = gcol >> 6, d = gcol & 63;
                    vtp[((size_t)(b * NHEAD + h) * HDIM + d) * SEQ + s] = f2bf(acc[i][j][r]);
                }
    }
}

// ---------------- flash attention ----------------
// grid (S/64, H, B); 4 waves; wave w handles q-rows [qt*64 + w*16, +16)
// kv-tiles with kvBase >= vlen are skipped (exact when vlen>=1: exp(-1e9-m) == 0)
__global__ __launch_bounds__(256) void attn_kernel(
        const unsigned short* __restrict__ qp, const unsigned short* __restrict__ kp,
        const unsigned short* __restrict__ vtp, const int* __restrict__ vlenp,
        float* __restrict__ out) {
    const int tid = threadIdx.x, lane = tid & 63, w = tid >> 6;
    const int qt = blockIdx.x, h = blockIdx.y, b = blockIdx.z;
    const int vlen = vlenp[b];
    const int ntiles = (vlen == 0) ? (SEQ / 64) : ((vlen + 63) >> 6);

    __shared__ unsigned short Ks[64 * 64];   // [key][d] swizzled
    __shared__ unsigned short Vs[64 * 64];   // [d][key] swizzled (V^T layout)
    __shared__ short Ps[4][16 * 64];         // per-wave P [q][key] swizzled

    const size_t headQ = (size_t)(b * NHEAD + h) * SEQ * HDIM;
    const size_t headV = (size_t)(b * NHEAD + h) * HDIM * SEQ;

    const int qrow = qt * 64 + w * 16 + (lane & 15);
    bf16x8 qf[2];
    #pragma unroll
    for (int ks = 0; ks < 2; ++ks)
        qf[ks] = *(const bf16x8*)(qp + headQ + (size_t)qrow * HDIM + ks * 32 + (lane >> 4) * 8);

    f32x4 acc_o[4];
    #pragma unroll
    for (int dt = 0; dt < 4; ++dt) acc_o[dt] = (f32x4){0.f, 0.f, 0.f, 0.f};
    float m_run[4] = {-1e30f, -1e30f, -1e30f, -1e30f};
    float l_run[4] = {0.f, 0.f, 0.f, 0.f};

    short* Pw = &Ps[w][0];

    const int rloc = lane >> 3;
    const int ssw  = ((lane & 7) * 8) ^ (rloc * 8);

    for (int kv = 0; kv < ntiles; ++kv) {
        const int kvBase = kv * 64;
        #pragma unroll
        for (int j = 0; j < 2; ++j) {
            int c = w * 2 + j;
            int r = c * 8 + rloc;
            gld16(kp  + headQ + (size_t)(kvBase + r) * HDIM + ssw, &Ks[c * 512]);
            gld16(vtp + headV + (size_t)r * SEQ + kvBase + ssw,    &Vs[c * 512]);
        }
        __syncthreads();

        // QK^T: sa[nt] rows=q (lane>>4)*4+reg, cols=key nt*16+(lane&15)
        f32x4 sa[4];
        #pragma unroll
        for (int nt = 0; nt < 4; ++nt) sa[nt] = (f32x4){0.f, 0.f, 0.f, 0.f};
        #pragma unroll
        for (int ks = 0; ks < 2; ++ks) {
            const int kbyte = ks * 64 + (lane >> 4) * 16;
            #pragma unroll
            for (int nt = 0; nt < 4; ++nt) {
                int kr = nt * 16 + (lane & 15);
                bf16x8 kf = *(const bf16x8*)((const char*)Ks + kr * 128 + (kbyte ^ ((kr & 7) << 4)));
                sa[nt] = MFMA16(qf[ks], kf, sa[nt], 0, 0, 0);
            }
        }

        // online softmax per q-row (reg r)
        const bool full = (kvBase + 64 <= vlen);
        float p[4][4];
        #pragma unroll
        for (int r = 0; r < 4; ++r) {
            float rmax = -1e30f;
            #pragma unroll
            for (int nt = 0; nt < 4; ++nt) {
                float sv = sa[nt][r] * 0.125f;
                if (!full && (kvBase + nt * 16 + (lane & 15) >= vlen)) sv = -1e9f;
                p[nt][r] = sv;
                rmax = fmaxf(rmax, sv);
            }
            #pragma unroll
            for (int m = 1; m < 16; m <<= 1) rmax = fmaxf(rmax, __shfl_xor(rmax, m));
            float mnew = fmaxf(m_run[r], rmax);
            float al = __expf(m_run[r] - mnew);
            float rs = 0.f;
            #pragma unroll
            for (int nt = 0; nt < 4; ++nt) {
                p[nt][r] = __expf(p[nt][r] - mnew);
                rs += p[nt][r];
            }
            #pragma unroll
            for (int m = 1; m < 16; m <<= 1) rs += __shfl_xor(rs, m);
            l_run[r] = l_run[r] * al + rs;
            m_run[r] = mnew;
            #pragma unroll
            for (int dt = 0; dt < 4; ++dt) acc_o[dt][r] *= al;
        }

        // P -> LDS (bf16, per-wave region; same-wave so no barrier needed)
        #pragma unroll
        for (int r = 0; r < 4; ++r)
            #pragma unroll
            for (int nt = 0; nt < 4; ++nt) {
                int pr = (lane >> 4) * 4 + r;
                int pc = nt * 16 + (lane & 15);
                *(unsigned short*)((char*)Pw + pr * 128 + ((pc * 2) ^ ((pr & 7) << 4))) = f2bf(p[nt][r]);
            }

        // PV: acc_o[dt] += P[16x64] @ V[64x(dt*16..)]
        #pragma unroll
        for (int ks = 0; ks < 2; ++ks) {
            const int kbyte = ks * 64 + (lane >> 4) * 16;
            int prr = lane & 15;
            bf16x8 pf = *(const bf16x8*)((const char*)Pw + prr * 128 + (kbyte ^ ((prr & 7) << 4)));
            #pragma unroll
            for (int dt = 0; dt < 4; ++dt) {
                int vr = dt * 16 + (lane & 15);
                bf16x8 vf = *(const bf16x8*)((const char*)Vs + vr * 128 + (kbyte ^ ((vr & 7) << 4)));
                acc_o[dt] = MFMA16(pf, vf, acc_o[dt], 0, 0, 0);
            }
        }
        __syncthreads();
    }

    #pragma unroll
    for (int r = 0; r < 4; ++r) {
        float inv = 1.0f / l_run[r];
        int s = qt * 64 + w * 16 + (lane >> 4) * 4 + r;
        #pragma unroll
        for (int dt = 0; dt < 4; ++dt) {
            int col = h * HDIM + dt * 16 + (lane & 15);
            out[(size_t)(b * SEQ + s) * DMODEL + col] = acc_o[dt][r] * inv;
        }
    }
}

extern "C" void kernel_launch(void* const* d_in, const int* in_sizes, int n_in,
                              void* d_out, int out_size, void* d_ws, size_t ws_size,
                              hipStream_t stream) {
    const float* Q  = (const float*)d_in[0];
    const float* K  = (const float*)d_in[1];
    const float* V  = (const float*)d_in[2];
    const int* V_len = (const int*)d_in[3];
    const float* WQ = (const float*)d_in[4];
    const float* WK = (const float*)d_in[5];
    const float* WV = (const float*)d_in[6];
    float* out = (float*)d_out;

    char* ws = (char*)d_ws;
    const size_t MB = 1024 * 1024;
    unsigned short* Xq  = (unsigned short*)(ws + 0 * MB);   // 8 MiB each
    unsigned short* Xk  = (unsigned short*)(ws + 8 * MB);
    unsigned short* Xv  = (unsigned short*)(ws + 16 * MB);
    unsigned short* WTq = (unsigned short*)(ws + 24 * MB);  // 2 MiB each
    unsigned short* WTk = (unsigned short*)(ws + 26 * MB);
    unsigned short* WTv = (unsigned short*)(ws + 28 * MB);
    unsigned short* qpj = (unsigned short*)(ws + 30 * MB);  // [B][H][S][D] 8 MiB
    unsigned short* kpj = (unsigned short*)(ws + 38 * MB);  // [B][H][S][D] 8 MiB
    unsigned short* vtp = (unsigned short*)(ws + 46 * MB);  // [B][H][D][S] 8 MiB

    const int n8 = ROWS * DMODEL / 8;  // 524288
    cvt_kernel<<<dim3((n8 + 255) / 256, 1, 3), 256, 0, stream>>>(Q, K, V, Xq, Xk, Xv, n8);
    wtrans_kernel<<<dim3(16, 16, 3), 256, 0, stream>>>(WQ, WK, WV, WTq, WTk, WTv);
    proj_kernel<<<dim3(DMODEL / 128, ROWS / 128, 3), 256, 0, stream>>>(
        Xq, Xk, Xv, WTq, WTk, WTv, qpj, kpj, vtp);
    attn_kernel<<<dim3(SEQ / 64, NHEAD, NBATCH), 256, 0, stream>>>(qpj, kpj, vtp, V_len, out);
}

// Round 3
// 108.799 us; speedup vs baseline: 2.5941x; 1.2512x over previous
//
#include <hip/hip_runtime.h>
#include <hip/hip_bf16.h>

#define NBATCH 2
#define SEQ 2048
#define DMODEL 1024
#define NHEAD 16
#define HDIM 64
#define ROWS (NBATCH*SEQ)

typedef __attribute__((ext_vector_type(8))) short bf16x8;
typedef __attribute__((ext_vector_type(4))) float f32x4;
typedef __attribute__((ext_vector_type(16))) float f32x16;

#define MFMA16 __builtin_amdgcn_mfma_f32_16x16x32_bf16
#define MFMA32 __builtin_amdgcn_mfma_f32_32x32x16_bf16

static __device__ __forceinline__ unsigned short f2bf(float f) {
    unsigned int u = __float_as_uint(f);
    u += 0x7fffu + ((u >> 16) & 1u);
    return (unsigned short)(u >> 16);
}

static __device__ __forceinline__ unsigned cvtpk(float lo, float hi) {
    unsigned r;
    asm("v_cvt_pk_bf16_f32 %0, %1, %2" : "=v"(r) : "v"(lo), "v"(hi));
    return r;
}

// async global->LDS, 16B per lane; LDS dest = wave-uniform base + lane*16
static __device__ __forceinline__ void gld16(const unsigned short* g, unsigned short* l) {
    __builtin_amdgcn_global_load_lds(
        (const __attribute__((address_space(1))) unsigned int*)g,
        (__attribute__((address_space(3))) unsigned int*)l,
        16, 0, 0);
}

// ---------------- fp32 -> bf16 convert, all three inputs in one launch ----------------
__global__ __launch_bounds__(256) void cvt_kernel(const float* __restrict__ Q, const float* __restrict__ K,
                                                  const float* __restrict__ V,
                                                  unsigned short* __restrict__ dq, unsigned short* __restrict__ dk,
                                                  unsigned short* __restrict__ dv, int n8) {
    int i = blockIdx.x * 256 + threadIdx.x;
    if (i >= n8) return;
    const float* src = blockIdx.z == 0 ? Q : (blockIdx.z == 1 ? K : V);
    unsigned short* dst = blockIdx.z == 0 ? dq : (blockIdx.z == 1 ? dk : dv);
    const float4* s4 = (const float4*)src;
    float4 a = s4[2 * i], b = s4[2 * i + 1];
    union { bf16x8 v; unsigned short u[8]; } o;
    o.u[0] = f2bf(a.x); o.u[1] = f2bf(a.y); o.u[2] = f2bf(a.z); o.u[3] = f2bf(a.w);
    o.u[4] = f2bf(b.x); o.u[5] = f2bf(b.y); o.u[6] = f2bf(b.z); o.u[7] = f2bf(b.w);
    *(bf16x8*)(dst + (size_t)i * 8) = o.v;
}

// ---------------- weight transpose + convert: WT[n][k] = bf16(W[k][n]) ----------------
__global__ __launch_bounds__(256) void wtrans_kernel(const float* __restrict__ W0, const float* __restrict__ W1,
                                                     const float* __restrict__ W2,
                                                     unsigned short* __restrict__ T0, unsigned short* __restrict__ T1,
                                                     unsigned short* __restrict__ T2) {
    const float* W = blockIdx.z == 0 ? W0 : (blockIdx.z == 1 ? W1 : W2);
    unsigned short* T = blockIdx.z == 0 ? T0 : (blockIdx.z == 1 ? T1 : T2);
    __shared__ float tile[64][65];
    int rb = blockIdx.y * 64, cb = blockIdx.x * 64;
    int tid = threadIdx.x;
    #pragma unroll
    for (int rep = 0; rep < 16; ++rep) {
        int idx = rep * 256 + tid; int r = idx >> 6, c = idx & 63;
        tile[r][c] = W[(size_t)(rb + r) * DMODEL + cb + c];
    }
    __syncthreads();
    #pragma unroll
    for (int rep = 0; rep < 16; ++rep) {
        int idx = rep * 256 + tid; int r = idx >> 6, c = idx & 63;
        T[(size_t)(cb + r) * DMODEL + rb + c] = f2bf(tile[c][r]);
    }
}

// ---------------- projection GEMM (m97 structure: global_load_lds, 2 barriers/k-tile) ----------------
// mode 0 (Q): C = 0.125 * X @ W (scale folded), scatter to [B][H][S][D] bf16
// mode 1 (K): C = X @ W, scatter to [B][H][S][D] bf16
// mode 2 (V): swapped operands (C^T), scatter to [B][H][D][S] bf16
__global__ __launch_bounds__(256) void proj_kernel(
        const unsigned short* __restrict__ Xq, const unsigned short* __restrict__ Xk,
        const unsigned short* __restrict__ Xv,
        const unsigned short* __restrict__ WTq, const unsigned short* __restrict__ WTk,
        const unsigned short* __restrict__ WTv,
        unsigned short* __restrict__ qp, unsigned short* __restrict__ kp,
        unsigned short* __restrict__ vtp) {
    const int mode = blockIdx.z;
    const unsigned short* X  = mode == 0 ? Xq  : (mode == 1 ? Xk  : Xv);
    const unsigned short* WT = mode == 0 ? WTq : (mode == 1 ? WTk : WTv);

    __shared__ unsigned short As[128 * 64];
    __shared__ unsigned short Bs[128 * 64];

    const int tid = threadIdx.x, lane = tid & 63, w = tid >> 6;
    const int wr = w >> 1, wc = w & 1;
    const int rowBase = blockIdx.y * 128;
    const int colBase = blockIdx.x * 128;

    const int Xwave = (mode < 2) ? wr : wc;
    const int Wwave = (mode < 2) ? wc : wr;

    const int rloc = lane >> 3;
    const int ssw  = ((lane & 7) * 8) ^ (rloc * 8);

    f32x4 acc[4][4];
    #pragma unroll
    for (int i = 0; i < 4; ++i)
        #pragma unroll
        for (int j = 0; j < 4; ++j) acc[i][j] = (f32x4){0.f, 0.f, 0.f, 0.f};

    for (int kt = 0; kt < DMODEL / 64; ++kt) {
        #pragma unroll
        for (int j = 0; j < 4; ++j) {
            int c = w * 4 + j;
            int r = c * 8 + rloc;
            gld16(X  + (size_t)(rowBase + r) * DMODEL + kt * 64 + ssw, &As[c * 512]);
            gld16(WT + (size_t)(colBase + r) * DMODEL + kt * 64 + ssw, &Bs[c * 512]);
        }
        __syncthreads();
        #pragma unroll
        for (int ks = 0; ks < 2; ++ks) {
            const int kbyte = ks * 64 + ((lane >> 4) * 16);
            bf16x8 xf[4], wf[4];
            #pragma unroll
            for (int i = 0; i < 4; ++i) {
                int xr = Xwave * 64 + i * 16 + (lane & 15);
                xf[i] = *(const bf16x8*)((const char*)As + xr * 128 + (kbyte ^ ((xr & 7) << 4)));
                int wrow = Wwave * 64 + i * 16 + (lane & 15);
                wf[i] = *(const bf16x8*)((const char*)Bs + wrow * 128 + (kbyte ^ ((wrow & 7) << 4)));
            }
            if (mode < 2) {
                #pragma unroll
                for (int i = 0; i < 4; ++i)
                    #pragma unroll
                    for (int j = 0; j < 4; ++j)
                        acc[i][j] = MFMA16(xf[i], wf[j], acc[i][j], 0, 0, 0);
            } else {
                #pragma unroll
                for (int i = 0; i < 4; ++i)
                    #pragma unroll
                    for (int j = 0; j < 4; ++j)
                        acc[i][j] = MFMA16(wf[i], xf[j], acc[i][j], 0, 0, 0);
            }
        }
        __syncthreads();
    }

    if (mode < 2) {
        unsigned short* outp = (mode == 0) ? qp : kp;
        const float sc = (mode == 0) ? 0.125f : 1.0f;  // fold 1/sqrt(D) into Q
        #pragma unroll
        for (int i = 0; i < 4; ++i)
            #pragma unroll
            for (int j = 0; j < 4; ++j)
                #pragma unroll
                for (int r = 0; r < 4; ++r) {
                    int grow = rowBase + wr * 64 + i * 16 + (lane >> 4) * 4 + r;  // b*S+s
                    int gcol = colBase + wc * 64 + j * 16 + (lane & 15);          // h*D+d
                    int b = grow >> 11, s = grow & 2047, hh = gcol >> 6, d = gcol & 63;
                    outp[((size_t)(b * NHEAD + hh) * SEQ + s) * HDIM + d] = f2bf(acc[i][j][r] * sc);
                }
    } else {
        #pragma unroll
        for (int i = 0; i < 4; ++i)
            #pragma unroll
            for (int j = 0; j < 4; ++j)
                #pragma unroll
                for (int r = 0; r < 4; ++r) {
                    int gcol = colBase + wr * 64 + i * 16 + (lane >> 4) * 4 + r;  // h*D+d
                    int grow = rowBase + wc * 64 + j * 16 + (lane & 15);          // b*S+s
                    int b = grow >> 11, s = grow & 2047, hh = gcol >> 6, d = gcol & 63;
                    vtp[((size_t)(b * NHEAD + hh) * HDIM + d) * SEQ + s] = f2bf(acc[i][j][r]);
                }
    }
}

// ---------------- flash attention, 32x32 swapped-QK^T in-register softmax ----------------
// grid (SEQ/128, H, B); 4 waves; wave w owns q-rows [qt*128 + w*32, +32)
// Swapped QK^T: s = mfma(K_frag, Q_frag) -> lane holds P[q=lane&31][16 keys per acc].
// PV computed transposed: o = mfma(VT_frag, P_frag) -> lane holds O[q=lane&31][16 d per tile].
__global__ __launch_bounds__(256) void attn_kernel(
        const unsigned short* __restrict__ qp, const unsigned short* __restrict__ kp,
        const unsigned short* __restrict__ vtp, const int* __restrict__ vlenp,
        float* __restrict__ out) {
    const int tid = threadIdx.x, lane = tid & 63, w = tid >> 6;
    const int hh = lane >> 5;          // wave half
    const int ql = lane & 31;          // this lane's q (col) / row index
    const int qt = blockIdx.x, h = blockIdx.y, b = blockIdx.z;
    const int vlen = vlenp[b];
    const int ntiles = (vlen == 0) ? (SEQ / 64) : ((vlen + 63) >> 6);

    __shared__ unsigned short Ks[64 * 64];   // [key][d] swizzled
    __shared__ unsigned short Vs[64 * 64];   // [d][key] swizzled (V^T)

    const size_t headQ = (size_t)(b * NHEAD + h) * SEQ * HDIM;
    const size_t headV = (size_t)(b * NHEAD + h) * HDIM * SEQ;

    // Q fragment (B-operand): lane holds Q[q=ql][d = ks*16 + hh*8 + j]
    const int qrow = qt * 128 + w * 32 + ql;
    bf16x8 qf[4];
    #pragma unroll
    for (int ks = 0; ks < 4; ++ks)
        qf[ks] = *(const bf16x8*)(qp + headQ + (size_t)qrow * HDIM + ks * 16 + hh * 8);

    f32x16 o0, o1;
    #pragma unroll
    for (int r = 0; r < 16; ++r) { o0[r] = 0.f; o1[r] = 0.f; }
    float m_run = -1e30f, l_run = 0.f;

    const int rloc = lane >> 3;
    const int ssw  = ((lane & 7) * 8) ^ (rloc * 8);

    for (int kv = 0; kv < ntiles; ++kv) {
        const int kvBase = kv * 64;
        #pragma unroll
        for (int j = 0; j < 2; ++j) {
            int c = w * 2 + j;
            int r = c * 8 + rloc;
            gld16(kp  + headQ + (size_t)(kvBase + r) * HDIM + ssw, &Ks[c * 512]);
            gld16(vtp + headV + (size_t)r * SEQ + kvBase + ssw,    &Vs[c * 512]);
        }
        __syncthreads();

        // QK^T swapped: s_t[q=ql][key = t*32 + (r&3)+8*(r>>2)+4*hh]
        f32x16 s0, s1;
        #pragma unroll
        for (int r = 0; r < 16; ++r) { s0[r] = 0.f; s1[r] = 0.f; }
        #pragma unroll
        for (int ks = 0; ks < 4; ++ks) {
            const int kb = (ks * 32 + hh * 16) ^ ((ql & 7) << 4);
            bf16x8 kf0 = *(const bf16x8*)((const char*)Ks + ql * 128 + kb);
            bf16x8 kf1 = *(const bf16x8*)((const char*)Ks + (32 + ql) * 128 + kb);
            s0 = MFMA32(kf0, qf[ks], s0, 0, 0, 0);
            s1 = MFMA32(kf1, qf[ks], s1, 0, 0, 0);
        }

        // mask (boundary tile only; wave-uniform branch)
        if (kvBase + 64 > vlen) {
            #pragma unroll
            for (int r = 0; r < 16; ++r) {
                int kl = (r & 3) + 8 * (r >> 2) + 4 * hh;
                if (kvBase + kl >= vlen)      s0[r] = -1e9f;
                if (kvBase + 32 + kl >= vlen) s1[r] = -1e9f;
            }
        }

        // online softmax: lane owns one q-row; keys split lane <-> lane^32
        float tmax = -1e30f;
        #pragma unroll
        for (int r = 0; r < 16; ++r) tmax = fmaxf(tmax, fmaxf(s0[r], s1[r]));
        tmax = fmaxf(tmax, __shfl_xor(tmax, 32));
        const float mnew = fmaxf(m_run, tmax);
        const float al = __expf(m_run - mnew);
        float ls = 0.f;
        #pragma unroll
        for (int r = 0; r < 16; ++r) {
            s0[r] = __expf(s0[r] - mnew); ls += s0[r];
            s1[r] = __expf(s1[r] - mnew); ls += s1[r];
        }
        ls += __shfl_xor(ls, 32);
        l_run = l_run * al + ls;
        m_run = mnew;
        #pragma unroll
        for (int r = 0; r < 16; ++r) { o0[r] *= al; o1[r] *= al; }

        // pack P to bf16 pairs (reg pairs 2i,2i+1 hold consecutive keys)
        unsigned d0[8], d1[8], x0[8], x1[8];
        #pragma unroll
        for (int i = 0; i < 8; ++i) {
            d0[i] = cvtpk(s0[2 * i], s0[2 * i + 1]);
            d1[i] = cvtpk(s1[2 * i], s1[2 * i + 1]);
        }
        #pragma unroll
        for (int i = 0; i < 8; ++i) {
            x0[i] = (unsigned)__shfl_xor((int)d0[i], 32);
            x1[i] = (unsigned)__shfl_xor((int)d1[i], 32);
        }

        // PV (transposed): for key-slice ksl, P-frag (B-op) lane needs
        // P[q=ql][key = ksl*16 + hh*8 + j]; assembled from d/x with static indices.
#define PV_SLICE(DD, XX, KSL)                                                      \
        {                                                                          \
            const int c = ((KSL) & 1) * 4;                                         \
            union { unsigned u[4]; bf16x8 v; } pa;                                 \
            pa.u[0] = hh ? XX[c + 2] : DD[c];                                      \
            pa.u[1] = hh ? XX[c + 3] : DD[c + 1];                                  \
            pa.u[2] = hh ? DD[c + 2] : XX[c];                                      \
            pa.u[3] = hh ? DD[c + 3] : XX[c + 1];                                  \
            const int vb = ((KSL) * 32 + hh * 16) ^ ((ql & 7) << 4);               \
            bf16x8 vf0 = *(const bf16x8*)((const char*)Vs + ql * 128 + vb);        \
            bf16x8 vf1 = *(const bf16x8*)((const char*)Vs + (32 + ql) * 128 + vb); \
            o0 = MFMA32(vf0, pa.v, o0, 0, 0, 0);                                   \
            o1 = MFMA32(vf1, pa.v, o1, 0, 0, 0);                                   \
        }
        PV_SLICE(d0, x0, 0)
        PV_SLICE(d0, x0, 1)
        PV_SLICE(d1, x1, 2)
        PV_SLICE(d1, x1, 3)
#undef PV_SLICE
        __syncthreads();
    }

    // epilogue: lane holds O[q=ql][d = dt*32 + 8*(r>>2) + 4*hh + (r&3)]
    const float inv = 1.0f / l_run;
    float* orow = out + (size_t)(b * SEQ + qrow) * DMODEL + h * HDIM;
    #pragma unroll
    for (int g = 0; g < 4; ++g) {
        float4 v0 = make_float4(o0[g * 4 + 0] * inv, o0[g * 4 + 1] * inv,
                                o0[g * 4 + 2] * inv, o0[g * 4 + 3] * inv);
        *(float4*)(orow + 8 * g + 4 * hh) = v0;
        float4 v1 = make_float4(o1[g * 4 + 0] * inv, o1[g * 4 + 1] * inv,
                                o1[g * 4 + 2] * inv, o1[g * 4 + 3] * inv);
        *(float4*)(orow + 32 + 8 * g + 4 * hh) = v1;
    }
}

extern "C" void kernel_launch(void* const* d_in, const int* in_sizes, int n_in,
                              void* d_out, int out_size, void* d_ws, size_t ws_size,
                              hipStream_t stream) {
    const float* Q  = (const float*)d_in[0];
    const float* K  = (const float*)d_in[1];
    const float* V  = (const float*)d_in[2];
    const int* V_len = (const int*)d_in[3];
    const float* WQ = (const float*)d_in[4];
    const float* WK = (const float*)d_in[5];
    const float* WV = (const float*)d_in[6];
    float* out = (float*)d_out;

    char* ws = (char*)d_ws;
    const size_t MB = 1024 * 1024;
    unsigned short* Xq  = (unsigned short*)(ws + 0 * MB);
    unsigned short* Xk  = (unsigned short*)(ws + 8 * MB);
    unsigned short* Xv  = (unsigned short*)(ws + 16 * MB);
    unsigned short* WTq = (unsigned short*)(ws + 24 * MB);
    unsigned short* WTk = (unsigned short*)(ws + 26 * MB);
    unsigned short* WTv = (unsigned short*)(ws + 28 * MB);
    unsigned short* qpj = (unsigned short*)(ws + 30 * MB);  // [B][H][S][D], pre-scaled by 1/8
    unsigned short* kpj = (unsigned short*)(ws + 38 * MB);  // [B][H][S][D]
    unsigned short* vtp = (unsigned short*)(ws + 46 * MB);  // [B][H][D][S]

    const int n8 = ROWS * DMODEL / 8;
    cvt_kernel<<<dim3((n8 + 255) / 256, 1, 3), 256, 0, stream>>>(Q, K, V, Xq, Xk, Xv, n8);
    wtrans_kernel<<<dim3(16, 16, 3), 256, 0, stream>>>(WQ, WK, WV, WTq, WTk, WTv);
    proj_kernel<<<dim3(DMODEL / 128, ROWS / 128, 3), 256, 0, stream>>>(
        Xq, Xk, Xv, WTq, WTk, WTv, qpj, kpj, vtp);
    attn_kernel<<<dim3(SEQ / 128, NHEAD, NBATCH), 256, 0, stream>>>(qpj, kpj, vtp, V_len, out);
}

// Round 4
// 104.037 us; speedup vs baseline: 2.7128x; 1.0458x over previous
//
#include <hip/hip_runtime.h>
#include <hip/hip_bf16.h>

#define NBATCH 2
#define SEQ 2048
#define DMODEL 1024
#define NHEAD 16
#define HDIM 64
#define ROWS (NBATCH*SEQ)

typedef __attribute__((ext_vector_type(8))) short bf16x8;
typedef __attribute__((ext_vector_type(4))) float f32x4;
typedef __attribute__((ext_vector_type(16))) float f32x16;

#define MFMA16 __builtin_amdgcn_mfma_f32_16x16x32_bf16
#define MFMA32 __builtin_amdgcn_mfma_f32_32x32x16_bf16

// Q-proj scale: (1/sqrt(64)) * log2(e)  -> softmax runs in exp2 domain
#define QSCALE 0.1803368801111204f
// defer-max threshold: 8 * log2(e)
#define DEFER_THR 11.541560327111708f

static __device__ __forceinline__ unsigned short f2bf(float f) {
    unsigned int u = __float_as_uint(f);
    u += 0x7fffu + ((u >> 16) & 1u);
    return (unsigned short)(u >> 16);
}

static __device__ __forceinline__ unsigned cvtpk(float lo, float hi) {
    unsigned r;
    asm("v_cvt_pk_bf16_f32 %0, %1, %2" : "=v"(r) : "v"(lo), "v"(hi));
    return r;
}

// async global->LDS, 16B per lane; LDS dest = wave-uniform base + lane*16
static __device__ __forceinline__ void gld16(const unsigned short* g, unsigned short* l) {
    __builtin_amdgcn_global_load_lds(
        (const __attribute__((address_space(1))) unsigned int*)g,
        (__attribute__((address_space(3))) unsigned int*)l,
        16, 0, 0);
}

// ---------------- fp32 -> bf16 convert, all three inputs in one launch ----------------
__global__ __launch_bounds__(256) void cvt_kernel(const float* __restrict__ Q, const float* __restrict__ K,
                                                  const float* __restrict__ V,
                                                  unsigned short* __restrict__ dq, unsigned short* __restrict__ dk,
                                                  unsigned short* __restrict__ dv, int n8) {
    int i = blockIdx.x * 256 + threadIdx.x;
    if (i >= n8) return;
    const float* src = blockIdx.z == 0 ? Q : (blockIdx.z == 1 ? K : V);
    unsigned short* dst = blockIdx.z == 0 ? dq : (blockIdx.z == 1 ? dk : dv);
    const float4* s4 = (const float4*)src;
    float4 a = s4[2 * i], b = s4[2 * i + 1];
    union { bf16x8 v; unsigned short u[8]; } o;
    o.u[0] = f2bf(a.x); o.u[1] = f2bf(a.y); o.u[2] = f2bf(a.z); o.u[3] = f2bf(a.w);
    o.u[4] = f2bf(b.x); o.u[5] = f2bf(b.y); o.u[6] = f2bf(b.z); o.u[7] = f2bf(b.w);
    *(bf16x8*)(dst + (size_t)i * 8) = o.v;
}

// ---------------- weight transpose + convert: WT[n][k] = bf16(W[k][n]) ----------------
__global__ __launch_bounds__(256) void wtrans_kernel(const float* __restrict__ W0, const float* __restrict__ W1,
                                                     const float* __restrict__ W2,
                                                     unsigned short* __restrict__ T0, unsigned short* __restrict__ T1,
                                                     unsigned short* __restrict__ T2) {
    const float* W = blockIdx.z == 0 ? W0 : (blockIdx.z == 1 ? W1 : W2);
    unsigned short* T = blockIdx.z == 0 ? T0 : (blockIdx.z == 1 ? T1 : T2);
    __shared__ float tile[64][65];
    int rb = blockIdx.y * 64, cb = blockIdx.x * 64;
    int tid = threadIdx.x;
    #pragma unroll
    for (int rep = 0; rep < 16; ++rep) {
        int idx = rep * 256 + tid; int r = idx >> 6, c = idx & 63;
        tile[r][c] = W[(size_t)(rb + r) * DMODEL + cb + c];
    }
    __syncthreads();
    #pragma unroll
    for (int rep = 0; rep < 16; ++rep) {
        int idx = rep * 256 + tid; int r = idx >> 6, c = idx & 63;
        T[(size_t)(cb + r) * DMODEL + rb + c] = f2bf(tile[c][r]);
    }
}

// ---------------- projection GEMM (m97 structure: global_load_lds, 2 barriers/k-tile) ----------------
// mode 0 (Q): C = QSCALE * X @ W, scatter to [B][H][S][D] bf16
// mode 1 (K): C = X @ W, scatter to [B][H][S][D] bf16
// mode 2 (V): swapped operands (C^T), scatter to [B][H][D][S] bf16
__global__ __launch_bounds__(256) void proj_kernel(
        const unsigned short* __restrict__ Xq, const unsigned short* __restrict__ Xk,
        const unsigned short* __restrict__ Xv,
        const unsigned short* __restrict__ WTq, const unsigned short* __restrict__ WTk,
        const unsigned short* __restrict__ WTv,
        unsigned short* __restrict__ qp, unsigned short* __restrict__ kp,
        unsigned short* __restrict__ vtp) {
    const int mode = blockIdx.z;
    const unsigned short* X  = mode == 0 ? Xq  : (mode == 1 ? Xk  : Xv);
    const unsigned short* WT = mode == 0 ? WTq : (mode == 1 ? WTk : WTv);

    __shared__ unsigned short As[128 * 64];
    __shared__ unsigned short Bs[128 * 64];

    const int tid = threadIdx.x, lane = tid & 63, w = tid >> 6;
    const int wr = w >> 1, wc = w & 1;
    const int rowBase = blockIdx.y * 128;
    const int colBase = blockIdx.x * 128;

    const int Xwave = (mode < 2) ? wr : wc;
    const int Wwave = (mode < 2) ? wc : wr;

    const int rloc = lane >> 3;
    const int ssw  = ((lane & 7) * 8) ^ (rloc * 8);

    f32x4 acc[4][4];
    #pragma unroll
    for (int i = 0; i < 4; ++i)
        #pragma unroll
        for (int j = 0; j < 4; ++j) acc[i][j] = (f32x4){0.f, 0.f, 0.f, 0.f};

    for (int kt = 0; kt < DMODEL / 64; ++kt) {
        #pragma unroll
        for (int j = 0; j < 4; ++j) {
            int c = w * 4 + j;
            int r = c * 8 + rloc;
            gld16(X  + (size_t)(rowBase + r) * DMODEL + kt * 64 + ssw, &As[c * 512]);
            gld16(WT + (size_t)(colBase + r) * DMODEL + kt * 64 + ssw, &Bs[c * 512]);
        }
        __syncthreads();
        #pragma unroll
        for (int ks = 0; ks < 2; ++ks) {
            const int kbyte = ks * 64 + ((lane >> 4) * 16);
            bf16x8 xf[4], wf[4];
            #pragma unroll
            for (int i = 0; i < 4; ++i) {
                int xr = Xwave * 64 + i * 16 + (lane & 15);
                xf[i] = *(const bf16x8*)((const char*)As + xr * 128 + (kbyte ^ ((xr & 7) << 4)));
                int wrow = Wwave * 64 + i * 16 + (lane & 15);
                wf[i] = *(const bf16x8*)((const char*)Bs + wrow * 128 + (kbyte ^ ((wrow & 7) << 4)));
            }
            if (mode < 2) {
                #pragma unroll
                for (int i = 0; i < 4; ++i)
                    #pragma unroll
                    for (int j = 0; j < 4; ++j)
                        acc[i][j] = MFMA16(xf[i], wf[j], acc[i][j], 0, 0, 0);
            } else {
                #pragma unroll
                for (int i = 0; i < 4; ++i)
                    #pragma unroll
                    for (int j = 0; j < 4; ++j)
                        acc[i][j] = MFMA16(wf[i], xf[j], acc[i][j], 0, 0, 0);
            }
        }
        __syncthreads();
    }

    if (mode < 2) {
        unsigned short* outp = (mode == 0) ? qp : kp;
        const float sc = (mode == 0) ? QSCALE : 1.0f;
        #pragma unroll
        for (int i = 0; i < 4; ++i)
            #pragma unroll
            for (int j = 0; j < 4; ++j)
                #pragma unroll
                for (int r = 0; r < 4; ++r) {
                    int grow = rowBase + wr * 64 + i * 16 + (lane >> 4) * 4 + r;  // b*S+s
                    int gcol = colBase + wc * 64 + j * 16 + (lane & 15);          // h*D+d
                    int b = grow >> 11, s = grow & 2047, hh = gcol >> 6, d = gcol & 63;
                    outp[((size_t)(b * NHEAD + hh) * SEQ + s) * HDIM + d] = f2bf(acc[i][j][r] * sc);
                }
    } else {
        #pragma unroll
        for (int i = 0; i < 4; ++i)
            #pragma unroll
            for (int j = 0; j < 4; ++j)
                #pragma unroll
                for (int r = 0; r < 4; ++r) {
                    int gcol = colBase + wr * 64 + i * 16 + (lane >> 4) * 4 + r;  // h*D+d
                    int grow = rowBase + wc * 64 + j * 16 + (lane & 15);          // b*S+s
                    int b = grow >> 11, s = grow & 2047, hh = gcol >> 6, d = gcol & 63;
                    vtp[((size_t)(b * NHEAD + hh) * HDIM + d) * SEQ + s] = f2bf(acc[i][j][r]);
                }
    }
}

// ---------------- flash attention, 32x32 swapped-QK^T, double-buffered, exp2 domain ----------------
// grid (SEQ/128, H, B); 4 waves; wave w owns q-rows [qt*128 + w*32, +32)
__global__ __launch_bounds__(256) void attn_kernel(
        const unsigned short* __restrict__ qp, const unsigned short* __restrict__ kp,
        const unsigned short* __restrict__ vtp, const int* __restrict__ vlenp,
        float* __restrict__ out) {
    const int tid = threadIdx.x, lane = tid & 63, w = tid >> 6;
    const int hh = lane >> 5;          // wave half
    const int ql = lane & 31;          // this lane's q (col) / frag row index
    const int qt = blockIdx.x, h = blockIdx.y, b = blockIdx.z;
    const int vlen = vlenp[b];
    const int ntiles = (vlen == 0) ? (SEQ / 64) : ((vlen + 63) >> 6);

    __shared__ unsigned short Ks[2][64 * 64];   // [key][d] swizzled, double-buffered
    __shared__ unsigned short Vs[2][64 * 64];   // [d][key] swizzled (V^T)

    const size_t headQ = (size_t)(b * NHEAD + h) * SEQ * HDIM;
    const size_t headV = (size_t)(b * NHEAD + h) * HDIM * SEQ;

    // Q fragment (B-operand): lane holds Q[q=ql][d = ks*16 + hh*8 + j]; pre-scaled by QSCALE
    const int qrow = qt * 128 + w * 32 + ql;
    bf16x8 qf[4];
    #pragma unroll
    for (int ks = 0; ks < 4; ++ks)
        qf[ks] = *(const bf16x8*)(qp + headQ + (size_t)qrow * HDIM + ks * 16 + hh * 8);

    f32x16 o0, o1;
    #pragma unroll
    for (int r = 0; r < 16; ++r) { o0[r] = 0.f; o1[r] = 0.f; }
    float m_run = -1e30f, l_run = 0.f;

    const int rloc = lane >> 3;
    const int ssw  = ((lane & 7) * 8) ^ (rloc * 8);
    const int c0 = w * 2, c1 = w * 2 + 1;
    const int r0 = c0 * 8 + rloc, r1 = c1 * 8 + rloc;

    // prologue: stage tile 0 into buffer 0
    {
        gld16(kp  + headQ + (size_t)r0 * HDIM + ssw, &Ks[0][c0 * 512]);
        gld16(kp  + headQ + (size_t)r1 * HDIM + ssw, &Ks[0][c1 * 512]);
        gld16(vtp + headV + (size_t)r0 * SEQ + ssw,  &Vs[0][c0 * 512]);
        gld16(vtp + headV + (size_t)r1 * SEQ + ssw,  &Vs[0][c1 * 512]);
    }
    __syncthreads();

    for (int kv = 0; kv < ntiles; ++kv) {
        const int kvBase = kv * 64;
        const int cur = kv & 1;

        // issue next-tile stage into the other buffer (latency hides under compute)
        if (kv + 1 < ntiles) {
            const int nb = kvBase + 64;
            gld16(kp  + headQ + (size_t)(nb + r0) * HDIM + ssw, &Ks[cur ^ 1][c0 * 512]);
            gld16(kp  + headQ + (size_t)(nb + r1) * HDIM + ssw, &Ks[cur ^ 1][c1 * 512]);
            gld16(vtp + headV + (size_t)r0 * SEQ + nb + ssw,    &Vs[cur ^ 1][c0 * 512]);
            gld16(vtp + headV + (size_t)r1 * SEQ + nb + ssw,    &Vs[cur ^ 1][c1 * 512]);
        }

        const unsigned short* Kb = &Ks[cur][0];
        const unsigned short* Vb = &Vs[cur][0];

        // QK^T swapped: s_t[q=ql][key = t*32 + (r&3)+8*(r>>2)+4*hh]  (exp2-domain scores)
        f32x16 s0, s1;
        #pragma unroll
        for (int r = 0; r < 16; ++r) { s0[r] = 0.f; s1[r] = 0.f; }
        __builtin_amdgcn_s_setprio(1);
        #pragma unroll
        for (int ks = 0; ks < 4; ++ks) {
            const int kb = (ks * 32 + hh * 16) ^ ((ql & 7) << 4);
            bf16x8 kf0 = *(const bf16x8*)((const char*)Kb + ql * 128 + kb);
            bf16x8 kf1 = *(const bf16x8*)((const char*)Kb + (32 + ql) * 128 + kb);
            s0 = MFMA32(kf0, qf[ks], s0, 0, 0, 0);
            s1 = MFMA32(kf1, qf[ks], s1, 0, 0, 0);
        }
        __builtin_amdgcn_s_setprio(0);

        // mask (boundary tile only; wave-uniform branch)
        if (kvBase + 64 > vlen) {
            #pragma unroll
            for (int r = 0; r < 16; ++r) {
                int kl = (r & 3) + 8 * (r >> 2) + 4 * hh;
                if (kvBase + kl >= vlen)      s0[r] = -1e9f;
                if (kvBase + 32 + kl >= vlen) s1[r] = -1e9f;
            }
        }

        // tile max (tree) + cross-half
        float mx[16];
        #pragma unroll
        for (int i = 0; i < 16; ++i) mx[i] = fmaxf(s0[i], s1[i]);
        #pragma unroll
        for (int st = 8; st > 0; st >>= 1)
            #pragma unroll
            for (int i = 0; i < st; ++i) mx[i] = fmaxf(mx[i], mx[i + st]);
        float tmax = fmaxf(mx[0], __shfl_xor(mx[0], 32));

        // defer-max: rescale only when the running max grows materially
        if (!__all(tmax <= m_run + DEFER_THR)) {
            const float mnew = fmaxf(m_run, tmax);
            const float al = __builtin_amdgcn_exp2f(m_run - mnew);
            l_run *= al;
            #pragma unroll
            for (int r = 0; r < 16; ++r) { o0[r] *= al; o1[r] *= al; }
            m_run = mnew;
        }

        // P = exp2(s - m) ; sum (tree)
        #pragma unroll
        for (int r = 0; r < 16; ++r) {
            s0[r] = __builtin_amdgcn_exp2f(s0[r] - m_run);
            s1[r] = __builtin_amdgcn_exp2f(s1[r] - m_run);
        }
        float sm[16];
        #pragma unroll
        for (int i = 0; i < 16; ++i) sm[i] = s0[i] + s1[i];
        #pragma unroll
        for (int st = 8; st > 0; st >>= 1)
            #pragma unroll
            for (int i = 0; i < st; ++i) sm[i] += sm[i + st];
        l_run += sm[0] + __shfl_xor(sm[0], 32);

        // pack P to bf16 pairs
        unsigned d0[8], d1[8];
        #pragma unroll
        for (int i = 0; i < 8; ++i) {
            d0[i] = cvtpk(s0[2 * i], s0[2 * i + 1]);
            d1[i] = cvtpk(s1[2 * i], s1[2 * i + 1]);
        }

        // PV (transposed): P-frag words via permlane32_swap:
        // swap(A=d[c], B=d[c+2]) -> A' = {own lo | partner lo} = pa.u[0],
        //                           B' = {partner hi | own hi} = pa.u[2]
        __builtin_amdgcn_s_setprio(1);
#define PV_SLICE(DD, KSL)                                                          \
        {                                                                          \
            const int c = ((KSL) & 1) * 4;                                         \
            unsigned a0 = DD[c],     b0 = DD[c + 2];                               \
            unsigned a1 = DD[c + 1], b1 = DD[c + 3];                               \
            asm("v_permlane32_swap_b32 %0, %1" : "+v"(a0), "+v"(b0));              \
            asm("v_permlane32_swap_b32 %0, %1" : "+v"(a1), "+v"(b1));              \
            union { unsigned u[4]; bf16x8 v; } pa;                                 \
            pa.u[0] = a0; pa.u[1] = a1; pa.u[2] = b0; pa.u[3] = b1;                \
            const int vb = ((KSL) * 32 + hh * 16) ^ ((ql & 7) << 4);               \
            bf16x8 vf0 = *(const bf16x8*)((const char*)Vb + ql * 128 + vb);        \
            bf16x8 vf1 = *(const bf16x8*)((const char*)Vb + (32 + ql) * 128 + vb); \
            o0 = MFMA32(vf0, pa.v, o0, 0, 0, 0);                                   \
            o1 = MFMA32(vf1, pa.v, o1, 0, 0, 0);                                   \
        }
        PV_SLICE(d0, 0)
        PV_SLICE(d0, 1)
        PV_SLICE(d1, 2)
        PV_SLICE(d1, 3)
#undef PV_SLICE
        __builtin_amdgcn_s_setprio(0);

        __syncthreads();  // buf cur free for re-stage; buf cur^1 staged (vmcnt drained)
    }

    // epilogue: lane holds O[q=ql][d = dt*32 + 8*(g) + 4*hh + (r&3)]
    const float inv = 1.0f / l_run;
    float* orow = out + (size_t)(b * SEQ + qrow) * DMODEL + h * HDIM;
    #pragma unroll
    for (int g = 0; g < 4; ++g) {
        float4 v0 = make_float4(o0[g * 4 + 0] * inv, o0[g * 4 + 1] * inv,
                                o0[g * 4 + 2] * inv, o0[g * 4 + 3] * inv);
        *(float4*)(orow + 8 * g + 4 * hh) = v0;
        float4 v1 = make_float4(o1[g * 4 + 0] * inv, o1[g * 4 + 1] * inv,
                                o1[g * 4 + 2] * inv, o1[g * 4 + 3] * inv);
        *(float4*)(orow + 32 + 8 * g + 4 * hh) = v1;
    }
}

extern "C" void kernel_launch(void* const* d_in, const int* in_sizes, int n_in,
                              void* d_out, int out_size, void* d_ws, size_t ws_size,
                              hipStream_t stream) {
    const float* Q  = (const float*)d_in[0];
    const float* K  = (const float*)d_in[1];
    const float* V  = (const float*)d_in[2];
    const int* V_len = (const int*)d_in[3];
    const float* WQ = (const float*)d_in[4];
    const float* WK = (const float*)d_in[5];
    const float* WV = (const float*)d_in[6];
    float* out = (float*)d_out;

    char* ws = (char*)d_ws;
    const size_t MB = 1024 * 1024;
    unsigned short* Xq  = (unsigned short*)(ws + 0 * MB);
    unsigned short* Xk  = (unsigned short*)(ws + 8 * MB);
    unsigned short* Xv  = (unsigned short*)(ws + 16 * MB);
    unsigned short* WTq = (unsigned short*)(ws + 24 * MB);
    unsigned short* WTk = (unsigned short*)(ws + 26 * MB);
    unsigned short* WTv = (unsigned short*)(ws + 28 * MB);
    unsigned short* qpj = (unsigned short*)(ws + 30 * MB);  // [B][H][S][D], pre-scaled (exp2 domain)
    unsigned short* kpj = (unsigned short*)(ws + 38 * MB);  // [B][H][S][D]
    unsigned short* vtp = (unsigned short*)(ws + 46 * MB);  // [B][H][D][S]

    const int n8 = ROWS * DMODEL / 8;
    cvt_kernel<<<dim3((n8 + 255) / 256, 1, 3), 256, 0, stream>>>(Q, K, V, Xq, Xk, Xv, n8);
    wtrans_kernel<<<dim3(16, 16, 3), 256, 0, stream>>>(WQ, WK, WV, WTq, WTk, WTv);
    proj_kernel<<<dim3(DMODEL / 128, ROWS / 128, 3), 256, 0, stream>>>(
        Xq, Xk, Xv, WTq, WTk, WTv, qpj, kpj, vtp);
    attn_kernel<<<dim3(SEQ / 128, NHEAD, NBATCH), 256, 0, stream>>>(qpj, kpj, vtp, V_len, out);
}

// Round 5
// 93.184 us; speedup vs baseline: 3.0288x; 1.1165x over previous
//
#include <hip/hip_runtime.h>
#include <hip/hip_bf16.h>

#define NBATCH 2
#define SEQ 2048
#define DMODEL 1024
#define NHEAD 16
#define HDIM 64
#define ROWS (NBATCH*SEQ)

typedef __attribute__((ext_vector_type(8))) short bf16x8;
typedef __attribute__((ext_vector_type(4))) float f32x4;
typedef __attribute__((ext_vector_type(16))) float f32x16;

#define MFMA16 __builtin_amdgcn_mfma_f32_16x16x32_bf16
#define MFMA32 __builtin_amdgcn_mfma_f32_32x32x16_bf16

// Q-proj scale: (1/sqrt(64)) * log2(e)  -> softmax runs in exp2 domain
#define QSCALE 0.1803368801111204f
// defer-max threshold: 8 * log2(e)
#define DEFER_THR 11.541560327111708f

static __device__ __forceinline__ unsigned short f2bf(float f) {
    unsigned int u = __float_as_uint(f);
    u += 0x7fffu + ((u >> 16) & 1u);
    return (unsigned short)(u >> 16);
}

static __device__ __forceinline__ unsigned cvtpk(float lo, float hi) {
    unsigned r;
    asm("v_cvt_pk_bf16_f32 %0, %1, %2" : "=v"(r) : "v"(lo), "v"(hi));
    return r;
}

// async global->LDS, 16B per lane; LDS dest = wave-uniform base + lane*16
static __device__ __forceinline__ void gld16(const unsigned short* g, unsigned short* l) {
    __builtin_amdgcn_global_load_lds(
        (const __attribute__((address_space(1))) unsigned int*)g,
        (__attribute__((address_space(3))) unsigned int*)l,
        16, 0, 0);
}

// ---------------- fp32 -> bf16 convert (V_len-aware skip for K/V rows) ----------------
__global__ __launch_bounds__(256) void cvt_kernel(const float* __restrict__ Q, const float* __restrict__ K,
                                                  const float* __restrict__ V, const int* __restrict__ vlenp,
                                                  unsigned short* __restrict__ dq, unsigned short* __restrict__ dk,
                                                  unsigned short* __restrict__ dv, int n8) {
    int i = blockIdx.x * 256 + threadIdx.x;
    if (i >= n8) return;
    const int z = blockIdx.z;
    if (z) {
        int row = i >> 7;                 // (i*8)/DMODEL
        int bb = row >> 11, s = row & 2047;
        int vl = vlenp[bb];
        int lim = ((vl + 31) >> 5) << 5;
        if (z == 1) { if (vl == 0 || s >= lim) return; }   // K rows >= ceil32(vlen) unused
        else        { if (vl != 0 && s >= lim) return; }   // V rows unused unless vlen==0
    }
    const float* src = z == 0 ? Q : (z == 1 ? K : V);
    unsigned short* dst = z == 0 ? dq : (z == 1 ? dk : dv);
    const float4* s4 = (const float4*)src;
    float4 a = s4[2 * i], b = s4[2 * i + 1];
    union { bf16x8 v; unsigned short u[8]; } o;
    o.u[0] = f2bf(a.x); o.u[1] = f2bf(a.y); o.u[2] = f2bf(a.z); o.u[3] = f2bf(a.w);
    o.u[4] = f2bf(b.x); o.u[5] = f2bf(b.y); o.u[6] = f2bf(b.z); o.u[7] = f2bf(b.w);
    *(bf16x8*)(dst + (size_t)i * 8) = o.v;
}

// ---------------- weight transpose + convert: WT[n][k] = bf16(W[k][n]) ----------------
__global__ __launch_bounds__(256) void wtrans_kernel(const float* __restrict__ W0, const float* __restrict__ W1,
                                                     const float* __restrict__ W2,
                                                     unsigned short* __restrict__ T0, unsigned short* __restrict__ T1,
                                                     unsigned short* __restrict__ T2) {
    const float* W = blockIdx.z == 0 ? W0 : (blockIdx.z == 1 ? W1 : W2);
    unsigned short* T = blockIdx.z == 0 ? T0 : (blockIdx.z == 1 ? T1 : T2);
    __shared__ float tile[64][65];
    int rb = blockIdx.y * 64, cb = blockIdx.x * 64;
    int tid = threadIdx.x;
    #pragma unroll
    for (int rep = 0; rep < 16; ++rep) {
        int idx = rep * 256 + tid; int r = idx >> 6, c = idx & 63;
        tile[r][c] = W[(size_t)(rb + r) * DMODEL + cb + c];
    }
    __syncthreads();
    #pragma unroll
    for (int rep = 0; rep < 16; ++rep) {
        int idx = rep * 256 + tid; int r = idx >> 6, c = idx & 63;
        T[(size_t)(cb + r) * DMODEL + rb + c] = f2bf(tile[c][r]);
    }
}

// ---------------- projection GEMM (m97 structure) with V_len-aware block skip ----------------
// mode 0 (Q): C = QSCALE * X @ W -> [B][H][S][D] bf16 (all rows)
// mode 1 (K): C = X @ W -> [B][H][S][D] bf16 (rows < ceil32(vlen); vlen==0 -> none)
// mode 2 (V): swapped operands (C^T) -> [B][H][D][S] bf16 (keys < ceil32(vlen); vlen==0 -> all)
__global__ __launch_bounds__(256) void proj_kernel(
        const unsigned short* __restrict__ Xq, const unsigned short* __restrict__ Xk,
        const unsigned short* __restrict__ Xv,
        const unsigned short* __restrict__ WTq, const unsigned short* __restrict__ WTk,
        const unsigned short* __restrict__ WTv, const int* __restrict__ vlenp,
        unsigned short* __restrict__ qp, unsigned short* __restrict__ kp,
        unsigned short* __restrict__ vtp) {
    const int mode = blockIdx.z;
    const int rowBase = blockIdx.y * 128;
    const int colBase = blockIdx.x * 128;

    if (mode >= 1) {
        const int bb = rowBase >> 11, sS = rowBase & 2047;
        const int vl = vlenp[bb];
        const int lim = ((vl + 31) >> 5) << 5;
        if (mode == 1) { if (vl == 0 || sS >= lim) return; }
        else           { if (vl != 0 && sS >= lim) return; }
    }

    const unsigned short* X  = mode == 0 ? Xq  : (mode == 1 ? Xk  : Xv);
    const unsigned short* WT = mode == 0 ? WTq : (mode == 1 ? WTk : WTv);

    __shared__ unsigned short As[128 * 64];
    __shared__ unsigned short Bs[128 * 64];

    const int tid = threadIdx.x, lane = tid & 63, w = tid >> 6;
    const int wr = w >> 1, wc = w & 1;

    const int Xwave = (mode < 2) ? wr : wc;
    const int Wwave = (mode < 2) ? wc : wr;

    const int rloc = lane >> 3;
    const int ssw  = ((lane & 7) * 8) ^ (rloc * 8);

    f32x4 acc[4][4];
    #pragma unroll
    for (int i = 0; i < 4; ++i)
        #pragma unroll
        for (int j = 0; j < 4; ++j) acc[i][j] = (f32x4){0.f, 0.f, 0.f, 0.f};

    for (int kt = 0; kt < DMODEL / 64; ++kt) {
        #pragma unroll
        for (int j = 0; j < 4; ++j) {
            int c = w * 4 + j;
            int r = c * 8 + rloc;
            gld16(X  + (size_t)(rowBase + r) * DMODEL + kt * 64 + ssw, &As[c * 512]);
            gld16(WT + (size_t)(colBase + r) * DMODEL + kt * 64 + ssw, &Bs[c * 512]);
        }
        __syncthreads();
        #pragma unroll
        for (int ks = 0; ks < 2; ++ks) {
            const int kbyte = ks * 64 + ((lane >> 4) * 16);
            bf16x8 xf[4], wf[4];
            #pragma unroll
            for (int i = 0; i < 4; ++i) {
                int xr = Xwave * 64 + i * 16 + (lane & 15);
                xf[i] = *(const bf16x8*)((const char*)As + xr * 128 + (kbyte ^ ((xr & 7) << 4)));
                int wrow = Wwave * 64 + i * 16 + (lane & 15);
                wf[i] = *(const bf16x8*)((const char*)Bs + wrow * 128 + (kbyte ^ ((wrow & 7) << 4)));
            }
            if (mode < 2) {
                #pragma unroll
                for (int i = 0; i < 4; ++i)
                    #pragma unroll
                    for (int j = 0; j < 4; ++j)
                        acc[i][j] = MFMA16(xf[i], wf[j], acc[i][j], 0, 0, 0);
            } else {
                #pragma unroll
                for (int i = 0; i < 4; ++i)
                    #pragma unroll
                    for (int j = 0; j < 4; ++j)
                        acc[i][j] = MFMA16(wf[i], xf[j], acc[i][j], 0, 0, 0);
            }
        }
        __syncthreads();
    }

    if (mode < 2) {
        unsigned short* outp = (mode == 0) ? qp : kp;
        const float sc = (mode == 0) ? QSCALE : 1.0f;
        #pragma unroll
        for (int i = 0; i < 4; ++i)
            #pragma unroll
            for (int j = 0; j < 4; ++j)
                #pragma unroll
                for (int r = 0; r < 4; ++r) {
                    int grow = rowBase + wr * 64 + i * 16 + (lane >> 4) * 4 + r;  // b*S+s
                    int gcol = colBase + wc * 64 + j * 16 + (lane & 15);          // h*D+d
                    int b = grow >> 11, s = grow & 2047, hh = gcol >> 6, d = gcol & 63;
                    outp[((size_t)(b * NHEAD + hh) * SEQ + s) * HDIM + d] = f2bf(acc[i][j][r] * sc);
                }
    } else {
        #pragma unroll
        for (int i = 0; i < 4; ++i)
            #pragma unroll
            for (int j = 0; j < 4; ++j)
                #pragma unroll
                for (int r = 0; r < 4; ++r) {
                    int gcol = colBase + wr * 64 + i * 16 + (lane >> 4) * 4 + r;  // h*D+d
                    int grow = rowBase + wc * 64 + j * 16 + (lane & 15);          // b*S+s
                    int b = grow >> 11, s = grow & 2047, hh = gcol >> 6, d = gcol & 63;
                    vtp[((size_t)(b * NHEAD + hh) * HDIM + d) * SEQ + s] = f2bf(acc[i][j][r]);
                }
    }
}

// ---------------- flash attention: split-KV per wave, barrier-free main loop ----------------
// grid (SEQ/64, H, B); 4 waves. wave w: qsub=w>>1 owns q-rows [qt*64+qsub*32, +32);
// kpar=w&1 handles 32-key tiles kpar, kpar+2, ... Per-wave K dbuf in LDS; V frags direct from L2.
// Epilogue: partner-wave (m,l,O) merge through LDS (reusing dead K buffers).
__global__ __launch_bounds__(256, 4) void attn_kernel(
        const unsigned short* __restrict__ qp, const unsigned short* __restrict__ kp,
        const unsigned short* __restrict__ vtp, const int* __restrict__ vlenp,
        float* __restrict__ out) {
    const int tid = threadIdx.x, lane = tid & 63, w = tid >> 6;
    const int hh = lane >> 5;          // wave half
    const int ql = lane & 31;          // this lane's q row (frag col)
    const int qsub = w >> 1, kpar = w & 1;
    const int qt = blockIdx.x, h = blockIdx.y, b = blockIdx.z;
    const int vlen = vlenp[b];
    const int nt = (vlen == 0) ? (SEQ / 32) : ((vlen + 31) >> 5);
    const int myn = (nt - kpar + 1) >> 1;   // tiles {kpar, kpar+2, ...} < nt

    __shared__ unsigned short Ks[4][2][32 * 64];  // per-wave K dbuf (4KB tiles), 32KB
    __shared__ float mlb[4][2][32];               // per-wave m,l

    const size_t headQ = (size_t)(b * NHEAD + h) * SEQ * HDIM;
    const size_t headV = (size_t)(b * NHEAD + h) * HDIM * SEQ;

    // Q fragment (B-operand): lane holds Q[q=ql][d = ks*16 + hh*8 + j]; pre-scaled (exp2 domain)
    const int qrow = qt * 64 + qsub * 32 + ql;
    bf16x8 qf[4];
    #pragma unroll
    for (int ks = 0; ks < 4; ++ks)
        qf[ks] = *(const bf16x8*)(qp + headQ + (size_t)qrow * HDIM + ks * 16 + hh * 8);

    f32x16 o0, o1;
    #pragma unroll
    for (int r = 0; r < 16; ++r) { o0[r] = 0.f; o1[r] = 0.f; }
    float m_run = -1e30f, l_run = 0.f;

    const int rloc = lane >> 3;
    const int ssw  = ((lane & 7) * 8) ^ (rloc * 8);

    auto stage = [&](int kvB, int buf) {
        #pragma unroll
        for (int c = 0; c < 4; ++c)
            gld16(kp + headQ + (size_t)(kvB + c * 8 + rloc) * HDIM + ssw, &Ks[w][buf][c * 512]);
    };

    if (myn > 0) stage(kpar * 32, 0);

    for (int i = 0; i < myn; ++i) {
        const int kvBase = (kpar + 2 * i) * 32;
        const int cur = i & 1;
        asm volatile("s_waitcnt vmcnt(0)" ::: "memory");   // K(i) staged (wave-local)

        // V fragments for this tile: direct 16B loads (L2-resident), issued early
        bf16x8 vf00 = *(const bf16x8*)(vtp + headV + (size_t)ql * SEQ + kvBase + hh * 8);
        bf16x8 vf01 = *(const bf16x8*)(vtp + headV + (size_t)(32 + ql) * SEQ + kvBase + hh * 8);
        bf16x8 vf10 = *(const bf16x8*)(vtp + headV + (size_t)ql * SEQ + kvBase + 16 + hh * 8);
        bf16x8 vf11 = *(const bf16x8*)(vtp + headV + (size_t)(32 + ql) * SEQ + kvBase + 16 + hh * 8);

        if (i + 1 < myn) stage(kvBase + 64, cur ^ 1);      // prefetch next tile

        // QK^T swapped: s0[q=ql][key = (r&3)+8*(r>>2)+4*hh]
        const char* Kb = (const char*)&Ks[w][cur][0];
        f32x16 s0;
        #pragma unroll
        for (int r = 0; r < 16; ++r) s0[r] = 0.f;
        __builtin_amdgcn_s_setprio(1);
        #pragma unroll
        for (int ks = 0; ks < 4; ++ks) {
            const int kb = (ks * 32 + hh * 16) ^ ((ql & 7) << 4);
            bf16x8 kf = *(const bf16x8*)(Kb + ql * 128 + kb);
            s0 = MFMA32(kf, qf[ks], s0, 0, 0, 0);
        }
        __builtin_amdgcn_s_setprio(0);

        // mask (boundary tile only; wave-uniform branch)
        if (kvBase + 32 > vlen) {
            #pragma unroll
            for (int r = 0; r < 16; ++r) {
                int kl = (r & 3) + 8 * (r >> 2) + 4 * hh;
                if (kvBase + kl >= vlen) s0[r] = -1e9f;
            }
        }

        // tile max (tree) + cross-half
        float mx[8];
        #pragma unroll
        for (int t = 0; t < 8; ++t) mx[t] = fmaxf(s0[t], s0[t + 8]);
        #pragma unroll
        for (int st = 4; st > 0; st >>= 1)
            #pragma unroll
            for (int t = 0; t < st; ++t) mx[t] = fmaxf(mx[t], mx[t + st]);
        float tmax = fmaxf(mx[0], __shfl_xor(mx[0], 32));

        // defer-max rescale
        if (!__all(tmax <= m_run + DEFER_THR)) {
            const float mnew = fmaxf(m_run, tmax);
            const float al = __builtin_amdgcn_exp2f(m_run - mnew);
            l_run *= al;
            #pragma unroll
            for (int r = 0; r < 16; ++r) { o0[r] *= al; o1[r] *= al; }
            m_run = mnew;
        }

        // P = exp2(s - m); sum (tree)
        #pragma unroll
        for (int r = 0; r < 16; ++r) s0[r] = __builtin_amdgcn_exp2f(s0[r] - m_run);
        float sm[8];
        #pragma unroll
        for (int t = 0; t < 8; ++t) sm[t] = s0[t] + s0[t + 8];
        #pragma unroll
        for (int st = 4; st > 0; st >>= 1)
            #pragma unroll
            for (int t = 0; t < st; ++t) sm[t] += sm[t + st];
        l_run += sm[0] + __shfl_xor(sm[0], 32);

        // pack P to bf16 pairs
        unsigned d0[8];
        #pragma unroll
        for (int t = 0; t < 8; ++t) d0[t] = cvtpk(s0[2 * t], s0[2 * t + 1]);

        // PV (transposed): P-frag words via permlane32_swap
        __builtin_amdgcn_s_setprio(1);
#define PV_SLICE(KSL, VFA, VFB)                                                    \
        {                                                                          \
            unsigned a0 = d0[4 * (KSL)],     b0 = d0[4 * (KSL) + 2];               \
            unsigned a1 = d0[4 * (KSL) + 1], b1 = d0[4 * (KSL) + 3];               \
            asm("v_permlane32_swap_b32 %0, %1" : "+v"(a0), "+v"(b0));              \
            asm("v_permlane32_swap_b32 %0, %1" : "+v"(a1), "+v"(b1));              \
            union { unsigned u[4]; bf16x8 v; } pa;                                 \
            pa.u[0] = a0; pa.u[1] = a1; pa.u[2] = b0; pa.u[3] = b1;                \
            o0 = MFMA32(VFA, pa.v, o0, 0, 0, 0);                                   \
            o1 = MFMA32(VFB, pa.v, o1, 0, 0, 0);                                   \
        }
        PV_SLICE(0, vf00, vf01)
        PV_SLICE(1, vf10, vf11)
#undef PV_SLICE
        __builtin_amdgcn_s_setprio(0);
    }

    // ---- cross-wave (key-parity) combine ----
    if (hh == 0) { mlb[w][0][ql] = m_run; mlb[w][1][ql] = l_run; }
    if (kpar == 1) {
        char* Ob = (char*)&Ks[w][0][0];   // 8KB dead K region: O[32 q][64 d] f32, swizzled
        #pragma unroll
        for (int g = 0; g < 4; ++g) {
            int ad = ql * 256 + ((32 * g + 16 * hh) ^ (16 * (ql & 7)));
            *(float4*)(Ob + ad)       = make_float4(o0[4*g], o0[4*g+1], o0[4*g+2], o0[4*g+3]);
            *(float4*)(Ob + ad + 128) = make_float4(o1[4*g], o1[4*g+1], o1[4*g+2], o1[4*g+3]);
        }
    }
    __syncthreads();
    if (kpar == 0) {
        const float mp = mlb[w + 1][0][ql], lp = mlb[w + 1][1][ql];
        const float M = fmaxf(m_run, mp);
        const float a0 = __builtin_amdgcn_exp2f(m_run - M);
        const float a1 = __builtin_amdgcn_exp2f(mp - M);
        const float linv = 1.0f / (l_run * a0 + lp * a1);
        const char* Pb = (const char*)&Ks[w + 1][0][0];
        float* orow = out + (size_t)(b * SEQ + qrow) * DMODEL + h * HDIM;
        #pragma unroll
        for (int g = 0; g < 4; ++g) {
            int ad = ql * 256 + ((32 * g + 16 * hh) ^ (16 * (ql & 7)));
            float4 p0 = *(const float4*)(Pb + ad);
            float4 p1 = *(const float4*)(Pb + ad + 128);
            *(float4*)(orow + 8 * g + 4 * hh) = make_float4(
                (o0[4*g]   * a0 + p0.x * a1) * linv, (o0[4*g+1] * a0 + p0.y * a1) * linv,
                (o0[4*g+2] * a0 + p0.z * a1) * linv, (o0[4*g+3] * a0 + p0.w * a1) * linv);
            *(float4*)(orow + 32 + 8 * g + 4 * hh) = make_float4(
                (o1[4*g]   * a0 + p1.x * a1) * linv, (o1[4*g+1] * a0 + p1.y * a1) * linv,
                (o1[4*g+2] * a0 + p1.z * a1) * linv, (o1[4*g+3] * a0 + p1.w * a1) * linv);
        }
    }
}

extern "C" void kernel_launch(void* const* d_in, const int* in_sizes, int n_in,
                              void* d_out, int out_size, void* d_ws, size_t ws_size,
                              hipStream_t stream) {
    const float* Q  = (const float*)d_in[0];
    const float* K  = (const float*)d_in[1];
    const float* V  = (const float*)d_in[2];
    const int* V_len = (const int*)d_in[3];
    const float* WQ = (const float*)d_in[4];
    const float* WK = (const float*)d_in[5];
    const float* WV = (const float*)d_in[6];
    float* out = (float*)d_out;

    char* ws = (char*)d_ws;
    const size_t MB = 1024 * 1024;
    unsigned short* Xq  = (unsigned short*)(ws + 0 * MB);
    unsigned short* Xk  = (unsigned short*)(ws + 8 * MB);
    unsigned short* Xv  = (unsigned short*)(ws + 16 * MB);
    unsigned short* WTq = (unsigned short*)(ws + 24 * MB);
    unsigned short* WTk = (unsigned short*)(ws + 26 * MB);
    unsigned short* WTv = (unsigned short*)(ws + 28 * MB);
    unsigned short* qpj = (unsigned short*)(ws + 30 * MB);  // [B][H][S][D], pre-scaled (exp2 domain)
    unsigned short* kpj = (unsigned short*)(ws + 38 * MB);  // [B][H][S][D]
    unsigned short* vtp = (unsigned short*)(ws + 46 * MB);  // [B][H][D][S]

    const int n8 = ROWS * DMODEL / 8;
    cvt_kernel<<<dim3((n8 + 255) / 256, 1, 3), 256, 0, stream>>>(Q, K, V, V_len, Xq, Xk, Xv, n8);
    wtrans_kernel<<<dim3(16, 16, 3), 256, 0, stream>>>(WQ, WK, WV, WTq, WTk, WTv);
    proj_kernel<<<dim3(DMODEL / 128, ROWS / 128, 3), 256, 0, stream>>>(
        Xq, Xk, Xv, WTq, WTk, WTv, V_len, qpj, kpj, vtp);
    attn_kernel<<<dim3(SEQ / 64, NHEAD, NBATCH), 256, 0, stream>>>(qpj, kpj, vtp, V_len, out);
}

// Round 6
// 86.226 us; speedup vs baseline: 3.2732x; 1.0807x over previous
//
#include <hip/hip_runtime.h>
#include <hip/hip_bf16.h>

#define NBATCH 2
#define SEQ 2048
#define DMODEL 1024
#define NHEAD 16
#define HDIM 64
#define ROWS (NBATCH*SEQ)

typedef __attribute__((ext_vector_type(8))) short bf16x8;
typedef __attribute__((ext_vector_type(4))) float f32x4;
typedef __attribute__((ext_vector_type(16))) float f32x16;

#define MFMA16 __builtin_amdgcn_mfma_f32_16x16x32_bf16
#define MFMA32 __builtin_amdgcn_mfma_f32_32x32x16_bf16

// Q-proj scale: (1/sqrt(64)) * log2(e)  -> softmax runs in exp2 domain
#define QSCALE 0.1803368801111204f
// defer-max threshold: 8 * log2(e)
#define DEFER_THR 11.541560327111708f

static __device__ __forceinline__ unsigned short f2bf(float f) {
    unsigned int u = __float_as_uint(f);
    u += 0x7fffu + ((u >> 16) & 1u);
    return (unsigned short)(u >> 16);
}

static __device__ __forceinline__ unsigned cvtpk(float lo, float hi) {
    unsigned r;
    asm("v_cvt_pk_bf16_f32 %0, %1, %2" : "=v"(r) : "v"(lo), "v"(hi));
    return r;
}

// async global->LDS, 16B per lane; LDS dest = wave-uniform base + lane*16
static __device__ __forceinline__ void gld16(const unsigned short* g, unsigned short* l) {
    __builtin_amdgcn_global_load_lds(
        (const __attribute__((address_space(1))) unsigned int*)g,
        (__attribute__((address_space(3))) unsigned int*)l,
        16, 0, 0);
}

// ---------------- fp32 -> bf16 convert (V_len-aware skip for K/V rows) ----------------
__global__ __launch_bounds__(256) void cvt_kernel(const float* __restrict__ Q, const float* __restrict__ K,
                                                  const float* __restrict__ V, const int* __restrict__ vlenp,
                                                  unsigned short* __restrict__ dq, unsigned short* __restrict__ dk,
                                                  unsigned short* __restrict__ dv, int n8) {
    int i = blockIdx.x * 256 + threadIdx.x;
    if (i >= n8) return;
    const int z = blockIdx.z;
    if (z) {
        int row = i >> 7;                 // (i*8)/DMODEL
        int bb = row >> 11, s = row & 2047;
        int vl = vlenp[bb];
        int lim = ((vl + 31) >> 5) << 5;
        if (z == 1) { if (vl == 0 || s >= lim) return; }   // K rows >= ceil32(vlen) unused
        else        { if (vl != 0 && s >= lim) return; }   // V rows unused unless vlen==0
    }
    const float* src = z == 0 ? Q : (z == 1 ? K : V);
    unsigned short* dst = z == 0 ? dq : (z == 1 ? dk : dv);
    const float4* s4 = (const float4*)src;
    float4 a = s4[2 * i], b = s4[2 * i + 1];
    union { bf16x8 v; unsigned short u[8]; } o;
    o.u[0] = f2bf(a.x); o.u[1] = f2bf(a.y); o.u[2] = f2bf(a.z); o.u[3] = f2bf(a.w);
    o.u[4] = f2bf(b.x); o.u[5] = f2bf(b.y); o.u[6] = f2bf(b.z); o.u[7] = f2bf(b.w);
    *(bf16x8*)(dst + (size_t)i * 8) = o.v;
}

// ---------------- weight transpose + convert: WT[n][k] = bf16(W[k][n]) ----------------
__global__ __launch_bounds__(256) void wtrans_kernel(const float* __restrict__ W0, const float* __restrict__ W1,
                                                     const float* __restrict__ W2,
                                                     unsigned short* __restrict__ T0, unsigned short* __restrict__ T1,
                                                     unsigned short* __restrict__ T2) {
    const float* W = blockIdx.z == 0 ? W0 : (blockIdx.z == 1 ? W1 : W2);
    unsigned short* T = blockIdx.z == 0 ? T0 : (blockIdx.z == 1 ? T1 : T2);
    __shared__ float tile[64][65];
    int rb = blockIdx.y * 64, cb = blockIdx.x * 64;
    int tid = threadIdx.x;
    #pragma unroll
    for (int rep = 0; rep < 16; ++rep) {
        int idx = rep * 256 + tid; int r = idx >> 6, c = idx & 63;
        tile[r][c] = W[(size_t)(rb + r) * DMODEL + cb + c];
    }
    __syncthreads();
    #pragma unroll
    for (int rep = 0; rep < 16; ++rep) {
        int idx = rep * 256 + tid; int r = idx >> 6, c = idx & 63;
        T[(size_t)(cb + r) * DMODEL + rb + c] = f2bf(tile[c][r]);
    }
}

// ---------------- projection GEMM (m97 structure) with V_len-aware block skip ----------------
__global__ __launch_bounds__(256) void proj_kernel(
        const unsigned short* __restrict__ Xq, const unsigned short* __restrict__ Xk,
        const unsigned short* __restrict__ Xv,
        const unsigned short* __restrict__ WTq, const unsigned short* __restrict__ WTk,
        const unsigned short* __restrict__ WTv, const int* __restrict__ vlenp,
        unsigned short* __restrict__ qp, unsigned short* __restrict__ kp,
        unsigned short* __restrict__ vtp) {
    const int mode = blockIdx.z;
    const int rowBase = blockIdx.y * 128;
    const int colBase = blockIdx.x * 128;

    if (mode >= 1) {
        const int bb = rowBase >> 11, sS = rowBase & 2047;
        const int vl = vlenp[bb];
        const int lim = ((vl + 31) >> 5) << 5;
        if (mode == 1) { if (vl == 0 || sS >= lim) return; }
        else           { if (vl != 0 && sS >= lim) return; }
    }

    const unsigned short* X  = mode == 0 ? Xq  : (mode == 1 ? Xk  : Xv);
    const unsigned short* WT = mode == 0 ? WTq : (mode == 1 ? WTk : WTv);

    __shared__ unsigned short As[128 * 64];
    __shared__ unsigned short Bs[128 * 64];

    const int tid = threadIdx.x, lane = tid & 63, w = tid >> 6;
    const int wr = w >> 1, wc = w & 1;

    const int Xwave = (mode < 2) ? wr : wc;
    const int Wwave = (mode < 2) ? wc : wr;

    const int rloc = lane >> 3;
    const int ssw  = ((lane & 7) * 8) ^ (rloc * 8);

    f32x4 acc[4][4];
    #pragma unroll
    for (int i = 0; i < 4; ++i)
        #pragma unroll
        for (int j = 0; j < 4; ++j) acc[i][j] = (f32x4){0.f, 0.f, 0.f, 0.f};

    for (int kt = 0; kt < DMODEL / 64; ++kt) {
        #pragma unroll
        for (int j = 0; j < 4; ++j) {
            int c = w * 4 + j;
            int r = c * 8 + rloc;
            gld16(X  + (size_t)(rowBase + r) * DMODEL + kt * 64 + ssw, &As[c * 512]);
            gld16(WT + (size_t)(colBase + r) * DMODEL + kt * 64 + ssw, &Bs[c * 512]);
        }
        __syncthreads();
        #pragma unroll
        for (int ks = 0; ks < 2; ++ks) {
            const int kbyte = ks * 64 + ((lane >> 4) * 16);
            bf16x8 xf[4], wf[4];
            #pragma unroll
            for (int i = 0; i < 4; ++i) {
                int xr = Xwave * 64 + i * 16 + (lane & 15);
                xf[i] = *(const bf16x8*)((const char*)As + xr * 128 + (kbyte ^ ((xr & 7) << 4)));
                int wrow = Wwave * 64 + i * 16 + (lane & 15);
                wf[i] = *(const bf16x8*)((const char*)Bs + wrow * 128 + (kbyte ^ ((wrow & 7) << 4)));
            }
            if (mode < 2) {
                #pragma unroll
                for (int i = 0; i < 4; ++i)
                    #pragma unroll
                    for (int j = 0; j < 4; ++j)
                        acc[i][j] = MFMA16(xf[i], wf[j], acc[i][j], 0, 0, 0);
            } else {
                #pragma unroll
                for (int i = 0; i < 4; ++i)
                    #pragma unroll
                    for (int j = 0; j < 4; ++j)
                        acc[i][j] = MFMA16(wf[i], xf[j], acc[i][j], 0, 0, 0);
            }
        }
        __syncthreads();
    }

    if (mode < 2) {
        unsigned short* outp = (mode == 0) ? qp : kp;
        const float sc = (mode == 0) ? QSCALE : 1.0f;
        #pragma unroll
        for (int i = 0; i < 4; ++i)
            #pragma unroll
            for (int j = 0; j < 4; ++j)
                #pragma unroll
                for (int r = 0; r < 4; ++r) {
                    int grow = rowBase + wr * 64 + i * 16 + (lane >> 4) * 4 + r;  // b*S+s
                    int gcol = colBase + wc * 64 + j * 16 + (lane & 15);          // h*D+d
                    int b = grow >> 11, s = grow & 2047, hh = gcol >> 6, d = gcol & 63;
                    outp[((size_t)(b * NHEAD + hh) * SEQ + s) * HDIM + d] = f2bf(acc[i][j][r] * sc);
                }
    } else {
        #pragma unroll
        for (int i = 0; i < 4; ++i)
            #pragma unroll
            for (int j = 0; j < 4; ++j)
                #pragma unroll
                for (int r = 0; r < 4; ++r) {
                    int gcol = colBase + wr * 64 + i * 16 + (lane >> 4) * 4 + r;  // h*D+d
                    int grow = rowBase + wc * 64 + j * 16 + (lane & 15);          // b*S+s
                    int b = grow >> 11, s = grow & 2047, hh = gcol >> 6, d = gcol & 63;
                    vtp[((size_t)(b * NHEAD + hh) * HDIM + d) * SEQ + s] = f2bf(acc[i][j][r]);
                }
    }
}

// ---------------- flash attention: shared-staged split-KV, 1 barrier/iter ----------------
// grid (SEQ/64, H, B); 4 waves. wave w: qsub=w>>1 (q-rows qt*64+qsub*32..+32), kpar=w&1
// (key tiles kpar, kpar+2, ...). Within each kpar chain the qsub0 wave stages K and the
// qsub1 wave stages V (both consume). Double-buffered; __syncthreads per iter is the
// producer-consumer handshake (its implicit per-wave vmcnt(0) drains each wave's own stage).
// V LDS layout: row r=d&31 (128B), granules 0-3 = d=r keys, 4-7 = d=r+32 keys; XOR swizzle
// gg = g ^ (r&7) applied via pre-swizzled global source (rule #21).
__global__ __launch_bounds__(256, 4) void attn_kernel(
        const unsigned short* __restrict__ qp, const unsigned short* __restrict__ kp,
        const unsigned short* __restrict__ vtp, const int* __restrict__ vlenp,
        float* __restrict__ out) {
    const int tid = threadIdx.x, lane = tid & 63, w = tid >> 6;
    const int hh = lane >> 5;          // wave half
    const int ql = lane & 31;          // this lane's q row (frag col)
    const int qsub = w >> 1, kpar = w & 1;
    const int qt = blockIdx.x, h = blockIdx.y, b = blockIdx.z;
    const int vlen = vlenp[b];
    const int nt = (vlen == 0) ? (SEQ / 32) : ((vlen + 31) >> 5);
    const int myn = (nt - kpar + 1) >> 1;   // tiles {kpar, kpar+2, ...} < nt
    const int J = (nt + 1) >> 1;            // uniform loop count (barrier safety)

    __shared__ unsigned short Kd[2][2][2048];  // [chain][buf][32 keys x 64 d], 16KB
    __shared__ unsigned short Vd[2][2][2048];  // [chain][buf][32 rows x 64 sh], 16KB
    __shared__ float mlb[4][2][32];

    const size_t headQ = (size_t)(b * NHEAD + h) * SEQ * HDIM;
    const size_t headV = (size_t)(b * NHEAD + h) * HDIM * SEQ;

    // Q fragment (B-operand): lane holds Q[q=ql][d = ks*16 + hh*8 + j]; pre-scaled (exp2 domain)
    const int qrow = qt * 64 + qsub * 32 + ql;
    bf16x8 qf[4];
    #pragma unroll
    for (int ks = 0; ks < 4; ++ks)
        qf[ks] = *(const bf16x8*)(qp + headQ + (size_t)qrow * HDIM + ks * 16 + hh * 8);

    f32x16 o0, o1;
    #pragma unroll
    for (int r = 0; r < 16; ++r) { o0[r] = 0.f; o1[r] = 0.f; }
    float m_run = -1e30f, l_run = 0.f;

    const int rloc = lane >> 3;                      // 0..7
    const int ssw  = ((lane & 7) * 8) ^ (rloc * 8);  // K-stage swizzled source (shorts)
    const int gn   = (lane & 7) ^ rloc;              // V-stage nominal granule
    const int koff = (gn & 3) * 8;                   // key offset within row (shorts)
    const int dhi  = (gn >> 2) * 32;                 // d-half select

    auto stageK = [&](int kvB, int buf) {
        #pragma unroll
        for (int c = 0; c < 4; ++c)
            gld16(kp + headQ + (size_t)(kvB + c * 8 + rloc) * HDIM + ssw, &Kd[kpar][buf][c * 512]);
    };
    auto stageV = [&](int kvB, int buf) {
        #pragma unroll
        for (int c = 0; c < 4; ++c)
            gld16(vtp + headV + (size_t)(c * 8 + rloc + dhi) * SEQ + kvB + koff, &Vd[kpar][buf][c * 512]);
    };

    if (myn > 0) { if (qsub == 0) stageK(kpar * 32, 0); else stageV(kpar * 32, 0); }

    for (int j = 0; j < J; ++j) {
        const int cur = j & 1;
        __syncthreads();   // my stage(j) drained (implicit vmcnt0); partner's too; buf cur^1 free

        if (j + 1 < myn) {
            const int nb = (kpar + 2 * (j + 1)) * 32;
            if (qsub == 0) stageK(nb, cur ^ 1); else stageV(nb, cur ^ 1);
        }

        if (j < myn) {
            const int kvBase = (kpar + 2 * j) * 32;
            const char* Kb = (const char*)&Kd[kpar][cur][0];
            const char* Vb = (const char*)&Vd[kpar][cur][0];

            // QK^T swapped: s0[q=ql][key = (r&3)+8*(r>>2)+4*hh]
            f32x16 s0;
            #pragma unroll
            for (int r = 0; r < 16; ++r) s0[r] = 0.f;
            __builtin_amdgcn_s_setprio(1);
            #pragma unroll
            for (int ks = 0; ks < 4; ++ks) {
                const int kb = (ks * 32 + hh * 16) ^ ((ql & 7) << 4);
                bf16x8 kf = *(const bf16x8*)(Kb + ql * 128 + kb);
                s0 = MFMA32(kf, qf[ks], s0, 0, 0, 0);
            }
            __builtin_amdgcn_s_setprio(0);

            // mask (boundary tile only; wave-uniform branch)
            if (kvBase + 32 > vlen) {
                #pragma unroll
                for (int r = 0; r < 16; ++r) {
                    int kl = (r & 3) + 8 * (r >> 2) + 4 * hh;
                    if (kvBase + kl >= vlen) s0[r] = -1e9f;
                }
            }

            // tile max (tree) + cross-half
            float mx[8];
            #pragma unroll
            for (int t = 0; t < 8; ++t) mx[t] = fmaxf(s0[t], s0[t + 8]);
            #pragma unroll
            for (int st = 4; st > 0; st >>= 1)
                #pragma unroll
                for (int t = 0; t < st; ++t) mx[t] = fmaxf(mx[t], mx[t + st]);
            float tmax = fmaxf(mx[0], __shfl_xor(mx[0], 32));

            // defer-max rescale
            if (!__all(tmax <= m_run + DEFER_THR)) {
                const float mnew = fmaxf(m_run, tmax);
                const float al = __builtin_amdgcn_exp2f(m_run - mnew);
                l_run *= al;
                #pragma unroll
                for (int r = 0; r < 16; ++r) { o0[r] *= al; o1[r] *= al; }
                m_run = mnew;
            }

            // P = exp2(s - m); sum (tree)
            #pragma unroll
            for (int r = 0; r < 16; ++r) s0[r] = __builtin_amdgcn_exp2f(s0[r] - m_run);
            float sm[8];
            #pragma unroll
            for (int t = 0; t < 8; ++t) sm[t] = s0[t] + s0[t + 8];
            #pragma unroll
            for (int st = 4; st > 0; st >>= 1)
                #pragma unroll
                for (int t = 0; t < st; ++t) sm[t] += sm[t + st];
            l_run += sm[0] + __shfl_xor(sm[0], 32);

            // pack P to bf16 pairs
            unsigned d0[8];
            #pragma unroll
            for (int t = 0; t < 8; ++t) d0[t] = cvtpk(s0[2 * t], s0[2 * t + 1]);

            // PV (transposed): A-frag rows d=ql (o0) / d=32+ql (o1) from swizzled Vd
            __builtin_amdgcn_s_setprio(1);
#define PV_SLICE(KSL)                                                              \
            {                                                                      \
                unsigned a0 = d0[4 * (KSL)],     b0 = d0[4 * (KSL) + 2];           \
                unsigned a1 = d0[4 * (KSL) + 1], b1 = d0[4 * (KSL) + 3];           \
                asm("v_permlane32_swap_b32 %0, %1" : "+v"(a0), "+v"(b0));          \
                asm("v_permlane32_swap_b32 %0, %1" : "+v"(a1), "+v"(b1));          \
                union { unsigned u[4]; bf16x8 v; } pa;                             \
                pa.u[0] = a0; pa.u[1] = a1; pa.u[2] = b0; pa.u[3] = b1;            \
                const int gA = 2 * (KSL) + hh;                                     \
                bf16x8 vfA = *(const bf16x8*)(Vb + ql * 128 + ((gA ^ (ql & 7)) << 4));        \
                bf16x8 vfB = *(const bf16x8*)(Vb + ql * 128 + (((4 + gA) ^ (ql & 7)) << 4));  \
                o0 = MFMA32(vfA, pa.v, o0, 0, 0, 0);                               \
                o1 = MFMA32(vfB, pa.v, o1, 0, 0, 0);                               \
            }
            PV_SLICE(0)
            PV_SLICE(1)
#undef PV_SLICE
            __builtin_amdgcn_s_setprio(0);
        }
    }

    // ---- cross-wave (key-parity) combine ----
    if (hh == 0) { mlb[w][0][ql] = m_run; mlb[w][1][ql] = l_run; }
    __syncthreads();   // everyone past last compute; Kd reusable as scratch
    if (kpar == 1) {
        char* Ob = ((char*)Kd) + qsub * 8192;   // O[32 q][64 d] f32, swizzled 256B rows
        #pragma unroll
        for (int g = 0; g < 4; ++g) {
            int ad = ql * 256 + ((32 * g + 16 * hh) ^ (16 * (ql & 7)));
            *(float4*)(Ob + ad)       = make_float4(o0[4*g], o0[4*g+1], o0[4*g+2], o0[4*g+3]);
            *(float4*)(Ob + ad + 128) = make_float4(o1[4*g], o1[4*g+1], o1[4*g+2], o1[4*g+3]);
        }
    }
    __syncthreads();
    if (kpar == 0) {
        const float mp = mlb[w + 1][0][ql], lp = mlb[w + 1][1][ql];
        const float M = fmaxf(m_run, mp);
        const float a0 = __builtin_amdgcn_exp2f(m_run - M);
        const float a1 = __builtin_amdgcn_exp2f(mp - M);
        const float linv = 1.0f / (l_run * a0 + lp * a1);
        const char* Pb = ((const char*)Kd) + qsub * 8192;
        float* orow = out + (size_t)(b * SEQ + qrow) * DMODEL + h * HDIM;
        #pragma unroll
        for (int g = 0; g < 4; ++g) {
            int ad = ql * 256 + ((32 * g + 16 * hh) ^ (16 * (ql & 7)));
            float4 p0 = *(const float4*)(Pb + ad);
            float4 p1 = *(const float4*)(Pb + ad + 128);
            *(float4*)(orow + 8 * g + 4 * hh) = make_float4(
                (o0[4*g]   * a0 + p0.x * a1) * linv, (o0[4*g+1] * a0 + p0.y * a1) * linv,
                (o0[4*g+2] * a0 + p0.z * a1) * linv, (o0[4*g+3] * a0 + p0.w * a1) * linv);
            *(float4*)(orow + 32 + 8 * g + 4 * hh) = make_float4(
                (o1[4*g]   * a0 + p1.x * a1) * linv, (o1[4*g+1] * a0 + p1.y * a1) * linv,
                (o1[4*g+2] * a0 + p1.z * a1) * linv, (o1[4*g+3] * a0 + p1.w * a1) * linv);
        }
    }
}

extern "C" void kernel_launch(void* const* d_in, const int* in_sizes, int n_in,
                              void* d_out, int out_size, void* d_ws, size_t ws_size,
                              hipStream_t stream) {
    const float* Q  = (const float*)d_in[0];
    const float* K  = (const float*)d_in[1];
    const float* V  = (const float*)d_in[2];
    const int* V_len = (const int*)d_in[3];
    const float* WQ = (const float*)d_in[4];
    const float* WK = (const float*)d_in[5];
    const float* WV = (const float*)d_in[6];
    float* out = (float*)d_out;

    char* ws = (char*)d_ws;
    const size_t MB = 1024 * 1024;
    unsigned short* Xq  = (unsigned short*)(ws + 0 * MB);
    unsigned short* Xk  = (unsigned short*)(ws + 8 * MB);
    unsigned short* Xv  = (unsigned short*)(ws + 16 * MB);
    unsigned short* WTq = (unsigned short*)(ws + 24 * MB);
    unsigned short* WTk = (unsigned short*)(ws + 26 * MB);
    unsigned short* WTv = (unsigned short*)(ws + 28 * MB);
    unsigned short* qpj = (unsigned short*)(ws + 30 * MB);  // [B][H][S][D], pre-scaled (exp2 domain)
    unsigned short* kpj = (unsigned short*)(ws + 38 * MB);  // [B][H][S][D]
    unsigned short* vtp = (unsigned short*)(ws + 46 * MB);  // [B][H][D][S]

    const int n8 = ROWS * DMODEL / 8;
    cvt_kernel<<<dim3((n8 + 255) / 256, 1, 3), 256, 0, stream>>>(Q, K, V, V_len, Xq, Xk, Xv, n8);
    wtrans_kernel<<<dim3(16, 16, 3), 256, 0, stream>>>(WQ, WK, WV, WTq, WTk, WTv);
    proj_kernel<<<dim3(DMODEL / 128, ROWS / 128, 3), 256, 0, stream>>>(
        Xq, Xk, Xv, WTq, WTk, WTv, V_len, qpj, kpj, vtp);
    attn_kernel<<<dim3(SEQ / 64, NHEAD, NBATCH), 256, 0, stream>>>(qpj, kpj, vtp, V_len, out);
}